// Round 17
// baseline (448.597 us; speedup 1.0000x reference)
//
#include <hip/hip_runtime.h>
#include <cstdint>
#include <cstddef>

#define N_NODES 16384
#define N_EDGES 65536
#define NFEAT 128   // GRU hidden
#define NIN   64    // node inputs
#define NEDGE 128   // edge features
#define NOUTD 64    // node outputs
#define NITERS 7

#define CHS 2080    // act chunk stride bytes (128 edges * 16B + 32B pad)

typedef _Float16 half8 __attribute__((ext_vector_type(8)));
typedef _Float16 half4 __attribute__((ext_vector_type(4)));
typedef float floatx4 __attribute__((ext_vector_type(4)));

#define MFMA16(a,b,c) __builtin_amdgcn_mfma_f32_16x16x32_f16((a),(b),(c),0,0,0)

// raw barrier (no vmcnt(0) drain, unlike __syncthreads)
#define SBAR() asm volatile("s_barrier" ::: "memory")
#define WAITLGKM() asm volatile("s_waitcnt lgkmcnt(0)" ::: "memory")
#define WAITV0() asm volatile("s_waitcnt vmcnt(0)" ::: "memory")

// async global->LDS, 16B per lane. Global src per-lane; LDS dest wave-uniform base (+lane*16 by HW).
__device__ __forceinline__ void load_lds16(const void* g, void* l){
  __builtin_amdgcn_global_load_lds(
      (__attribute__((address_space(1))) void*)(uintptr_t)g,
      (__attribute__((address_space(3))) void*)l,
      16, 0, 0);
}

// ---------------- one-shot setup: inits + fp16 weight repack + bias concat ----------------
// repack: W (NOUT x KIN) f32 row-major -> [KIN/8][NOUT][8] f16
__global__ void setup_kernel(
    const float* __restrict__ node_inputs,
    const float* __restrict__ W1, const float* __restrict__ W2,
    const float* __restrict__ W3, const float* __restrict__ W4,
    const float* __restrict__ W_ih, const float* __restrict__ W_hh,
    const float* __restrict__ W_f,
    const float* __restrict__ b1, const float* __restrict__ b2,
    const float* __restrict__ b3, const float* __restrict__ b4,
    _Float16* __restrict__ h16,
    _Float16* __restrict__ nin16,
    _Float16* __restrict__ W1s, _Float16* __restrict__ W2s, _Float16* __restrict__ W3s,
    _Float16* __restrict__ W4s, _Float16* __restrict__ Wihs, _Float16* __restrict__ Whhs,
    _Float16* __restrict__ Wfs, float* __restrict__ msgbias, int* __restrict__ cnt){
  int b = blockIdx.x, t = threadIdx.x;
  if (b < 8192){ int i=b*256+t; h16[i]=(_Float16)0.f; return; }
  b -= 8192;
  if (b < 4096){ int i=b*256+t; nin16[i] = (_Float16)node_inputs[i]; return; }
  b -= 4096;
  if (b < 64){ cnt[b*256+t] = 0; return; }
  b -= 64;
  if (b >= 176){  // bias concat: b1|b2|b3|b4 -> msgbias[1024] (zero-padded)
    int i = (b-176)*256 + t;
    float v = 0.f;
    if      (i < 256) v = b1[i];
    else if (i < 512) v = b2[i-256];
    else if (i < 768) v = b3[i-512];
    else if (i < 896) v = b4[i-768];
    msgbias[i] = v; return;
  }
  const float* W; _Float16* o; int NO, KI, base;
  if      (b < 32){ W=W1;  o=W1s;  NO=256; KI=256; base=b; }
  else if (b < 64){ W=W2;  o=W2s;  NO=256; KI=256; base=b-32; }
  else if (b < 96){ W=W3;  o=W3s;  NO=256; KI=256; base=b-64; }
  else if (b <112){ W=W4;  o=W4s;  NO=128; KI=256; base=b-96; }
  else if (b <148){ W=W_ih;o=Wihs; NO=384; KI=192; base=b-112; }
  else if (b <172){ W=W_hh;o=Whhs; NO=384; KI=128; base=b-148; }
  else            { W=W_f; o=Wfs;  NO=64;  KI=128; base=b-172; }
  int g = base*256 + t;
  int total = NO*(KI>>3);
  if (g >= total) return;
  int c = g/NO, j = g - c*NO;
  #pragma unroll
  for (int i=0;i<8;++i) o[(size_t)g*8+i] = (_Float16)W[(size_t)j*KI + c*8 + i];
}

__global__ void hist_kernel(const int* __restrict__ dst, int* __restrict__ cnt){
  int e = blockIdx.x*256+threadIdx.x; if (e<N_EDGES) atomicAdd(&cnt[dst[e]],1);
}
__global__ __launch_bounds__(1024) void scan_kernel(const int* __restrict__ cnt,
                                                    int* __restrict__ rowptr,
                                                    int* __restrict__ offs){
  __shared__ int sd[1024];
  int t = threadIdx.x;
  int c[16]; int s=0;
  #pragma unroll
  for (int k=0;k<16;++k){ c[k]=cnt[t*16+k]; s+=c[k]; }
  sd[t]=s; __syncthreads();
  for (int off=1; off<1024; off<<=1){
    int v = (t>=off)? sd[t-off]:0;
    __syncthreads();
    sd[t]+=v;
    __syncthreads();
  }
  int base = sd[t]-s; // exclusive prefix
  #pragma unroll
  for (int k=0;k<16;++k){ rowptr[t*16+k]=base; offs[t*16+k]=base; base+=c[k]; }
  if (t==0) rowptr[N_NODES]=N_EDGES;
}
// CSR permutation: src/dst ids in CSR-slot order -> msg writes message rows
// contiguously in dst-grouped order (agg reads sequentially).
__global__ void scatter_kernel(const int* __restrict__ src, const int* __restrict__ dst,
                               int* __restrict__ offs,
                               int* __restrict__ src_csr, int* __restrict__ dst_csr){
  int e = blockIdx.x*256+threadIdx.x;
  if (e<N_EDGES){
    int d = dst[e];
    int p = atomicAdd(&offs[d],1);
    src_csr[p] = src[e];
    dst_csr[p] = d;
  }
}

// ---------------- fused 4-layer edge MLP: 128 edges/block, 4 waves, 2 blocks/CU --------
// act LDS: [32 chunks][128 edges][8 halfs], chunk stride CHS (padded).
// Wave grid = 1M x 4N: each wave owns ALL 128 edges x N/4 cols, so B fragments are
// DISJOINT across waves. B frags: global(L2) -> VGPR, double-buffered one K-step
// ahead. No in-loop barriers.
template<int N, int NEXTN>
__device__ __forceinline__ void run_layer(const _Float16* __restrict__ Ws,
                                          const _Float16* __restrict__ nextWs,
                                          const char* act, half8 (&b)[2][4],
                                          int wave, int lane, floatx4 (&acc)[8][4]){
  constexpr int NTW  = N/64;                    // B frags per wave (disjoint cols)
  constexpr int NNTW = (NEXTN>0)? NEXTN/64 : 0;
  const int kg = lane>>4, col = lane&15;
  const int j0  = wave*(N/4);
  const int j0n = wave*(NEXTN/4);
  #pragma unroll
  for (int kk=0; kk<8; ++kk){
    if (kk < 7){
      #pragma unroll
      for (int nt=0; nt<NTW; ++nt)
        b[(kk+1)&1][nt] = *(const half8*)&Ws[(size_t)(((kk+1)*4+kg)*N + j0 + nt*16 + col)*8];
    } else if constexpr (NEXTN > 0){
      #pragma unroll
      for (int nt=0; nt<NNTW; ++nt)
        b[0][nt] = *(const half8*)&nextWs[(size_t)(kg*NEXTN + j0n + nt*16 + col)*8];
    }
    half8 a[8];
    #pragma unroll
    for (int mt=0; mt<8; ++mt)
      a[mt] = *(const half8*)(act + (size_t)(kk*4+kg)*CHS + (mt*16 + col)*16);
    __builtin_amdgcn_s_setprio(1);
    #pragma unroll
    for (int nt=0; nt<NTW; ++nt)
      #pragma unroll
      for (int mt=0; mt<8; ++mt)
        acc[mt][nt] = MFMA16(a[mt], b[kk&1][nt], acc[mt][nt]);
    __builtin_amdgcn_s_setprio(0);
  }
}

template<int NTW>
__device__ __forceinline__ void epi_relu(floatx4 (&acc)[8][4], const float* __restrict__ biasf,
                                         int boff, char* act, int wave, int lane){
  const int rg = lane>>4, col = lane&15;
  #pragma unroll
  for (int nt=0; nt<NTW; ++nt){
    int j = wave*(NTW*16) + nt*16 + col;
    float bv = biasf[boff + j];        // LDS read (lgkm) -- keeps vmcnt clean
    char* dst = act + (size_t)(j>>3)*CHS + (j&7)*2;
    #pragma unroll
    for (int mt=0; mt<8; ++mt){
      #pragma unroll
      for (int r=0; r<4; ++r){
        int e = mt*16 + rg*4 + r;
        float v = fmaxf(acc[mt][nt][r] + bv, 0.f);
        acc[mt][nt][r] = 0.f;
        *(_Float16*)(dst + (size_t)e*16) = (_Float16)v;
      }
    }
  }
}

__global__ __launch_bounds__(256,2) void msg_kernel(
    const _Float16* __restrict__ h,
    const int* __restrict__ src_csr, const int* __restrict__ dst_csr,
    const _Float16* __restrict__ W1s, const _Float16* __restrict__ W2s,
    const _Float16* __restrict__ W3s, const _Float16* __restrict__ W4s,
    const float* __restrict__ msgbias,
    _Float16* __restrict__ messages){
  __shared__ __align__(16) char smem[32*CHS + 4096];   // 69.5KB -> 2 blocks/CU
  char* act = smem;
  const float* biasf = (const float*)(smem + 32*CHS);
  const int t = threadIdx.x, wave = t>>6, lane = t&63;
  const int kg = lane>>4, col = lane&15;
  const int e0 = blockIdx.x*128;
  // stage bias concat (1024 floats; wave w loads 1KB)
  load_lds16((const char*)msgbias + wave*1024 + lane*16, smem + 32*CHS + wave*1024);
  // gather msg_in = [h[src] | h[dst]] into act chunks (0..15 src, 16..31 dst)
  {
    const int* ids = (wave < 2) ? src_csr : dst_csr;
    const int row0 = ids[e0 + lane]      * NFEAT;
    const int row1 = ids[e0 + 64 + lane] * NFEAT;
    #pragma unroll
    for (int i=0;i<8;++i){
      int c = wave*8 + i;
      int f = (c&15)*8;
      load_lds16(h + row0 + f, act + (size_t)c*CHS);
      load_lds16(h + row1 + f, act + (size_t)c*CHS + 1024);
    }
  }
  // L1 K-step-0 B prefetch (global -> regs): wave owns cols wave*64..+63
  half8 b[2][4];
  #pragma unroll
  for (int nt=0; nt<4; ++nt)
    b[0][nt] = *(const half8*)&W1s[(size_t)(kg*256 + wave*64 + nt*16 + col)*8];

  floatx4 acc[8][4];
  const floatx4 fz = {0.f,0.f,0.f,0.f};
  #pragma unroll
  for (int i=0;i<8;++i)
    #pragma unroll
    for (int j=0;j<4;++j) acc[i][j] = fz;

  WAITV0(); SBAR();                    // act + bias staged everywhere

  run_layer<256,256>(W1s, W2s, act, b, wave, lane, acc);
  WAITLGKM(); SBAR();                  // all waves' act reads done
  epi_relu<4>(acc, biasf, 0, act, wave, lane);
  WAITLGKM(); SBAR();                  // epi writes visible
  run_layer<256,256>(W2s, W3s, act, b, wave, lane, acc);
  WAITLGKM(); SBAR();
  epi_relu<4>(acc, biasf, 256, act, wave, lane);
  WAITLGKM(); SBAR();
  run_layer<256,128>(W3s, W4s, act, b, wave, lane, acc);
  WAITLGKM(); SBAR();
  epi_relu<4>(acc, biasf, 512, act, wave, lane);
  WAITLGKM(); SBAR();
  run_layer<128,0>(W4s, nullptr, act, b, wave, lane, acc);
  // L4 epilogue -> messages in CSR-slot order (contiguous rows), includes b4
  // wave owns cols wave*32..+31, all 128 edges
  {
    const int rg = lane>>4;
    #pragma unroll
    for (int nt=0; nt<2; ++nt){
      int j = wave*32 + nt*16 + col;
      float bv = biasf[768 + j];
      #pragma unroll
      for (int mt=0; mt<8; ++mt){
        #pragma unroll
        for (int r=0; r<4; ++r){
          int e = e0 + mt*16 + rg*4 + r;
          messages[(size_t)e*NEDGE + j] = (_Float16)(acc[mt][nt][r] + bv);
        }
      }
    }
  }
}

// ---------------- fused agg + GRU + output projection: 32 nodes, 256 threads ----------
// Multi-block/CU (grid 512): burst-agg made this phase throughput-shaped, so block
// parallelism now hides the L3 latency (round-12's regression predates the burst).
// agg: fixed burst of 8 clamped-index loads per node (len<=8 covers ~97%; tail loops).
// h is pure-fp16 recurrent state; h_old from A2 LDS (read-before-write bijective).
__global__ __launch_bounds__(256,2) void gru_kernel(
    const _Float16* __restrict__ messages,
    const int* __restrict__ rowptr,
    const _Float16* __restrict__ nin16,
    _Float16* __restrict__ h16,
    const _Float16* __restrict__ Wihs, const _Float16* __restrict__ Whhs,
    const _Float16* __restrict__ Wfs,
    const float* __restrict__ b_ih, const float* __restrict__ b_hh,
    const float* __restrict__ b_f,
    float* __restrict__ out){
  __shared__ _Float16 A1[24*32*8];   // 12KB: chunks 0..15 agg, 16..23 node inputs
  __shared__ _Float16 A2[16*32*8];   // 8KB: h rows (K=128); later reused for h_new
  const int t = threadIdx.x, wave = t>>6, lane = t&63;
  const int kg = lane>>4, col = lane&15;
  const int n0 = blockIdx.x*32;
  {
    const int node = lane&31;
    // nin chunks 16..23: wave w stages chunks 16+2w,16+2w+1 in one 1KB gload_lds
    load_lds16(nin16 + (size_t)(n0+node)*NIN + (wave*2 + (lane>>5))*8,
               (char*)A1 + 8192 + (size_t)wave*1024);
    // h chunks 0..15 of A2: wave w stages 4 chunks (2 gload_lds)
    #pragma unroll
    for (int ii=0; ii<2; ++ii){
      int cb = wave*4 + ii*2;
      load_lds16(h16 + (size_t)(n0+node)*NFEAT + (cb + (lane>>5))*8,
                 (char*)A2 + (size_t)cb*512);
    }
  }
  // agg: burst-predicated CSR gather -> A1 chunks 0..15
  {
    const int slot = t>>4, chunk = t&15, l8 = (t&15)*8;  // 16 slots x 16 feat-lanes
    #pragma unroll
    for (int rr=0; rr<2; ++rr){
      const int nl = rr*16 + slot;
      const int beg = rowptr[n0 + nl], end = rowptr[n0 + nl + 1];
      const int len = end - beg;
      const int safe = (beg < N_EDGES) ? beg : (N_EDGES-1);
      half8 v[8];
      #pragma unroll
      for (int k=0; k<8; ++k){
        int idx = beg + k;
        idx = (idx < end) ? idx : safe;          // clamped: always a valid address
        v[k] = *(const half8*)(messages + (size_t)idx*NEDGE + l8);
      }
      float a[8] = {0.f,0.f,0.f,0.f,0.f,0.f,0.f,0.f};
      #pragma unroll
      for (int k=0; k<8; ++k){
        if (k < len){
          #pragma unroll
          for (int q=0; q<8; ++q) a[q] += (float)v[k][q];
        }
      }
      for (int idx = beg+8; idx < end; ++idx){   // rare tail (len>8)
        half8 w = *(const half8*)(messages + (size_t)idx*NEDGE + l8);
        #pragma unroll
        for (int q=0; q<8; ++q) a[q] += (float)w[q];
      }
      half8 o;
      #pragma unroll
      for (int q=0; q<8; ++q) o[q] = (_Float16)a[q];
      *(half8*)&A1[((size_t)chunk*32 + nl)*8] = o;
    }
  }
  floatx4 gi[3][2][2], gh[3][2][2];
  const floatx4 fz = {0.f,0.f,0.f,0.f};
  #pragma unroll
  for (int g=0; g<3; ++g)
    #pragma unroll
    for (int nt=0; nt<2; ++nt)
      #pragma unroll
      for (int mt=0; mt<2; ++mt){ gi[g][nt][mt]=fz; gh[g][nt][mt]=fz; }

  __syncthreads();   // staging (vmcnt) + agg ds_writes (lgkm) all visible

  // wave w owns features w*32..w*32+31 (all 3 gates); B direct from L2
  #pragma unroll
  for (int kk=0; kk<6; ++kk){
    half8 a[2];
    #pragma unroll
    for (int mt=0;mt<2;++mt)
      a[mt] = *(const half8*)&A1[(((kk*4+kg)*32) + mt*16 + col)*8];
    #pragma unroll
    for (int g=0; g<3; ++g)
      #pragma unroll
      for (int nt=0; nt<2; ++nt){
        int j = g*128 + wave*32 + nt*16 + col;
        half8 b = *(const half8*)&Wihs[(size_t)((kk*4+kg)*384 + j)*8];
        #pragma unroll
        for (int mt=0;mt<2;++mt)
          gi[g][nt][mt] = MFMA16(a[mt], b, gi[g][nt][mt]);
      }
  }
  #pragma unroll
  for (int kk=0; kk<4; ++kk){
    half8 a[2];
    #pragma unroll
    for (int mt=0;mt<2;++mt)
      a[mt] = *(const half8*)&A2[(((kk*4+kg)*32) + mt*16 + col)*8];
    #pragma unroll
    for (int g=0; g<3; ++g)
      #pragma unroll
      for (int nt=0; nt<2; ++nt){
        int j = g*128 + wave*32 + nt*16 + col;
        half8 b = *(const half8*)&Whhs[(size_t)((kk*4+kg)*384 + j)*8];
        #pragma unroll
        for (int mt=0;mt<2;++mt)
          gh[g][nt][mt] = MFMA16(a[mt], b, gh[g][nt][mt]);
      }
  }
  __syncthreads();   // all A2 (h_old) MFMA reads done before overwrite

  // gates + h update; h_old from A2 LDS (read-before-write, unique slot per thread);
  // h_new -> global fp16 and back into A2 for the W_f GEMM
  #pragma unroll
  for (int nt=0; nt<2; ++nt){
    int jl = wave*32 + nt*16 + col;     // feature 0..127
    float bir=b_ih[jl], biz=b_ih[128+jl], bin_=b_ih[256+jl];
    float bhr=b_hh[jl], bhz=b_hh[128+jl], bhn=b_hh[256+jl];
    #pragma unroll
    for (int mt=0; mt<2; ++mt){
      #pragma unroll
      for (int r=0; r<4; ++r){
        int e = mt*16 + kg*4 + r;
        float ir = gi[0][nt][mt][r] + bir;
        float iz = gi[1][nt][mt][r] + biz;
        float inn= gi[2][nt][mt][r] + bin_;
        float hr = gh[0][nt][mt][r] + bhr;
        float hz = gh[1][nt][mt][r] + bhz;
        float hn = gh[2][nt][mt][r] + bhn;
        float rg2 = 1.f/(1.f+__expf(-(ir+hr)));
        float zg  = 1.f/(1.f+__expf(-(iz+hz)));
        float ng  = tanhf(inn + rg2*hn);
        size_t slot2 = (size_t)(((jl>>3)*32) + e)*8 + (jl&7);
        float hold = (float)A2[slot2];
        float hnew = (1.f-zg)*ng + zg*hold;
        h16[(size_t)(n0+e)*NFEAT + jl] = (_Float16)hnew;
        A2[slot2] = (_Float16)hnew;
      }
    }
  }
  __syncthreads();

  // out = h_new @ W_f^T + b_f  (K=128 -> 64 cols; ALL 4 waves used, 16 cols each)
  {
    floatx4 facc[2] = {fz, fz};
    #pragma unroll
    for (int kk=0; kk<4; ++kk){
      half8 a[2];
      #pragma unroll
      for (int mt=0;mt<2;++mt)
        a[mt] = *(const half8*)&A2[(((kk*4+kg)*32) + mt*16 + col)*8];
      half8 b = *(const half8*)&Wfs[(size_t)((kk*4+kg)*64 + wave*16 + col)*8];
      #pragma unroll
      for (int mt=0;mt<2;++mt)
        facc[mt] = MFMA16(a[mt], b, facc[mt]);
    }
    float bf = b_f[wave*16+col];
    #pragma unroll
    for (int mt=0; mt<2; ++mt){
      #pragma unroll
      for (int r=0; r<4; ++r){
        int e = mt*16 + kg*4 + r;
        out[(size_t)(n0+e)*NOUTD + wave*16 + col] = facc[mt][r] + bf;
      }
    }
  }
}

// ---------------- launch ----------------
extern "C" void kernel_launch(void* const* d_in, const int* in_sizes, int n_in,
                              void* d_out, int out_size, void* d_ws, size_t ws_size,
                              hipStream_t stream){
  (void)in_sizes; (void)n_in; (void)out_size; (void)ws_size;
  const float* node_inputs = (const float*)d_in[0];
  const int*   src_ids = (const int*)d_in[1];
  const int*   dst_ids = (const int*)d_in[2];
  const float* W1 = (const float*)d_in[3];  const float* b1 = (const float*)d_in[4];
  const float* W2 = (const float*)d_in[5];  const float* b2 = (const float*)d_in[6];
  const float* W3 = (const float*)d_in[7];  const float* b3 = (const float*)d_in[8];
  const float* W4 = (const float*)d_in[9];  const float* b4 = (const float*)d_in[10];
  const float* W_ih = (const float*)d_in[11];
  const float* W_hh = (const float*)d_in[12];
  const float* b_ih = (const float*)d_in[13];
  const float* b_hh = (const float*)d_in[14];
  const float* W_f  = (const float*)d_in[15];
  const float* b_f  = (const float*)d_in[16];
  float* out = (float*)d_out;

  char* ws = (char*)d_ws;
  auto alloc = [&](size_t b){ char* p = ws; ws += (b + 255) & ~(size_t)255; return p; };
  _Float16* h16  = (_Float16*)alloc((size_t)N_NODES*NFEAT*2);
  _Float16* nin16= (_Float16*)alloc((size_t)N_NODES*NIN*2);
  _Float16* msgs = (_Float16*)alloc((size_t)N_EDGES*NEDGE*2);
  _Float16* W1s  = (_Float16*)alloc(256*256*2);
  _Float16* W2s  = (_Float16*)alloc(256*256*2);
  _Float16* W3s  = (_Float16*)alloc(256*256*2);
  _Float16* W4s  = (_Float16*)alloc(128*256*2);
  _Float16* Wihs = (_Float16*)alloc(384*192*2);
  _Float16* Whhs = (_Float16*)alloc(384*128*2);
  _Float16* Wfs  = (_Float16*)alloc(64*128*2);
  float* msgbias = (float*)alloc(1024*4);
  int* cnt     = (int*)alloc((size_t)N_NODES*4);
  int* rowptr  = (int*)alloc((size_t)(N_NODES+1)*4);
  int* offs    = (int*)alloc((size_t)N_NODES*4);
  int* src_csr = (int*)alloc((size_t)N_EDGES*4);
  int* dst_csr = (int*)alloc((size_t)N_EDGES*4);

  setup_kernel<<<8192+4096+64+176+4,256,0,stream>>>(
      node_inputs, W1,W2,W3,W4, W_ih,W_hh,W_f, b1,b2,b3,b4,
      h16, nin16, W1s,W2s,W3s,W4s, Wihs,Whhs,Wfs, msgbias, cnt);
  hist_kernel<<<N_EDGES/256,256,0,stream>>>(dst_ids, cnt);
  scan_kernel<<<1,1024,0,stream>>>(cnt, rowptr, offs);
  scatter_kernel<<<N_EDGES/256,256,0,stream>>>(src_ids, dst_ids, offs, src_csr, dst_csr);

  for (int it=0; it<NITERS; ++it){
    msg_kernel<<<N_EDGES/128,256,0,stream>>>(h16, src_csr, dst_csr,
                                             W1s,W2s,W3s,W4s, msgbias, msgs);
    gru_kernel<<<N_NODES/32,256,0,stream>>>(msgs, rowptr, nin16, h16,
                                            Wihs, Whhs, Wfs, b_ih, b_hh, b_f,
                                            out + (size_t)it*N_NODES*NOUTD);
  }
}

// Round 18
// 368.321 us; speedup vs baseline: 1.2180x; 1.2180x over previous
//
#include <hip/hip_runtime.h>
#include <cstdint>
#include <cstddef>

#define N_NODES 16384
#define N_EDGES 65536
#define NFEAT 128   // GRU hidden
#define NIN   64    // node inputs
#define NEDGE 128   // edge features
#define NOUTD 64    // node outputs
#define NITERS 7

#define CHS 2080    // act chunk stride bytes (128 edges * 16B + 32B pad)

typedef _Float16 half8 __attribute__((ext_vector_type(8)));
typedef _Float16 half4 __attribute__((ext_vector_type(4)));
typedef float floatx4 __attribute__((ext_vector_type(4)));

#define MFMA16(a,b,c) __builtin_amdgcn_mfma_f32_16x16x32_f16((a),(b),(c),0,0,0)

// raw barrier (no vmcnt(0) drain, unlike __syncthreads)
#define SBAR() asm volatile("s_barrier" ::: "memory")
#define WAITLGKM() asm volatile("s_waitcnt lgkmcnt(0)" ::: "memory")
#define WAITV0() asm volatile("s_waitcnt vmcnt(0)" ::: "memory")

// async global->LDS, 16B per lane. Global src per-lane; LDS dest wave-uniform base (+lane*16 by HW).
__device__ __forceinline__ void load_lds16(const void* g, void* l){
  __builtin_amdgcn_global_load_lds(
      (__attribute__((address_space(1))) void*)(uintptr_t)g,
      (__attribute__((address_space(3))) void*)l,
      16, 0, 0);
}

// ---------------- one-shot setup: inits + fp16 weight repack + bias concat ----------------
// repack: W (NOUT x KIN) f32 row-major -> [KIN/8][NOUT][8] f16
__global__ void setup_kernel(
    const float* __restrict__ node_inputs,
    const float* __restrict__ W1, const float* __restrict__ W2,
    const float* __restrict__ W3, const float* __restrict__ W4,
    const float* __restrict__ W_ih, const float* __restrict__ W_hh,
    const float* __restrict__ W_f,
    const float* __restrict__ b1, const float* __restrict__ b2,
    const float* __restrict__ b3, const float* __restrict__ b4,
    _Float16* __restrict__ h16,
    _Float16* __restrict__ nin16,
    _Float16* __restrict__ W1s, _Float16* __restrict__ W2s, _Float16* __restrict__ W3s,
    _Float16* __restrict__ W4s, _Float16* __restrict__ Wihs, _Float16* __restrict__ Whhs,
    _Float16* __restrict__ Wfs, float* __restrict__ msgbias, int* __restrict__ cnt){
  int b = blockIdx.x, t = threadIdx.x;
  if (b < 8192){ int i=b*256+t; h16[i]=(_Float16)0.f; return; }
  b -= 8192;
  if (b < 4096){ int i=b*256+t; nin16[i] = (_Float16)node_inputs[i]; return; }
  b -= 4096;
  if (b < 64){ cnt[b*256+t] = 0; return; }
  b -= 64;
  if (b >= 176){  // bias concat: b1|b2|b3|b4 -> msgbias[1024] (zero-padded)
    int i = (b-176)*256 + t;
    float v = 0.f;
    if      (i < 256) v = b1[i];
    else if (i < 512) v = b2[i-256];
    else if (i < 768) v = b3[i-512];
    else if (i < 896) v = b4[i-768];
    msgbias[i] = v; return;
  }
  const float* W; _Float16* o; int NO, KI, base;
  if      (b < 32){ W=W1;  o=W1s;  NO=256; KI=256; base=b; }
  else if (b < 64){ W=W2;  o=W2s;  NO=256; KI=256; base=b-32; }
  else if (b < 96){ W=W3;  o=W3s;  NO=256; KI=256; base=b-64; }
  else if (b <112){ W=W4;  o=W4s;  NO=128; KI=256; base=b-96; }
  else if (b <148){ W=W_ih;o=Wihs; NO=384; KI=192; base=b-112; }
  else if (b <172){ W=W_hh;o=Whhs; NO=384; KI=128; base=b-148; }
  else            { W=W_f; o=Wfs;  NO=64;  KI=128; base=b-172; }
  int g = base*256 + t;
  int total = NO*(KI>>3);
  if (g >= total) return;
  int c = g/NO, j = g - c*NO;
  #pragma unroll
  for (int i=0;i<8;++i) o[(size_t)g*8+i] = (_Float16)W[(size_t)j*KI + c*8 + i];
}

// iteration-0 shortcut: h0 == 0 -> every edge's message is the same vector
// m0 = L4(relu(L3(relu(L2(relu(b1)))))) (bias-only chain). One block computes it.
__global__ __launch_bounds__(256) void mlp0_kernel(
    const float* __restrict__ W2, const float* __restrict__ W3,
    const float* __restrict__ W4,
    const float* __restrict__ b1, const float* __restrict__ b2,
    const float* __restrict__ b3, const float* __restrict__ b4,
    _Float16* __restrict__ m0){
  __shared__ float x1[256], x2[256], x3[256];
  const int t = threadIdx.x;
  x1[t] = fmaxf(b1[t], 0.f);
  __syncthreads();
  float s = b2[t];
  for (int k=0;k<256;++k) s += W2[(size_t)t*256+k]*x1[k];
  x2[t] = fmaxf(s, 0.f);
  __syncthreads();
  s = b3[t];
  for (int k=0;k<256;++k) s += W3[(size_t)t*256+k]*x2[k];
  x3[t] = fmaxf(s, 0.f);
  __syncthreads();
  if (t < 128){
    s = b4[t];
    for (int k=0;k<256;++k) s += W4[(size_t)t*256+k]*x3[k];
    m0[t] = (_Float16)s;
  }
}

__global__ void hist_kernel(const int* __restrict__ dst, int* __restrict__ cnt){
  int e = blockIdx.x*256+threadIdx.x; if (e<N_EDGES) atomicAdd(&cnt[dst[e]],1);
}
__global__ __launch_bounds__(1024) void scan_kernel(const int* __restrict__ cnt,
                                                    int* __restrict__ rowptr,
                                                    int* __restrict__ offs){
  __shared__ int sd[1024];
  int t = threadIdx.x;
  int c[16]; int s=0;
  #pragma unroll
  for (int k=0;k<16;++k){ c[k]=cnt[t*16+k]; s+=c[k]; }
  sd[t]=s; __syncthreads();
  for (int off=1; off<1024; off<<=1){
    int v = (t>=off)? sd[t-off]:0;
    __syncthreads();
    sd[t]+=v;
    __syncthreads();
  }
  int base = sd[t]-s; // exclusive prefix
  #pragma unroll
  for (int k=0;k<16;++k){ rowptr[t*16+k]=base; offs[t*16+k]=base; base+=c[k]; }
  if (t==0) rowptr[N_NODES]=N_EDGES;
}
// CSR permutation: src/dst ids in CSR-slot order -> msg writes message rows
// contiguously in dst-grouped order (agg reads sequentially).
__global__ void scatter_kernel(const int* __restrict__ src, const int* __restrict__ dst,
                               int* __restrict__ offs,
                               int* __restrict__ src_csr, int* __restrict__ dst_csr){
  int e = blockIdx.x*256+threadIdx.x;
  if (e<N_EDGES){
    int d = dst[e];
    int p = atomicAdd(&offs[d],1);
    src_csr[p] = src[e];
    dst_csr[p] = d;
  }
}

// ---------------- fused 4-layer edge MLP: 128 edges/block, 4 waves, 2 blocks/CU --------
// act LDS: [32 chunks][128 edges][8 halfs], chunk stride CHS (padded).
// Wave grid = 1M x 4N: each wave owns ALL 128 edges x N/4 cols, so B fragments are
// DISJOINT across waves. B frags: global(L2) -> VGPR, double-buffered one K-step
// ahead. No in-loop barriers.
template<int N, int NEXTN>
__device__ __forceinline__ void run_layer(const _Float16* __restrict__ Ws,
                                          const _Float16* __restrict__ nextWs,
                                          const char* act, half8 (&b)[2][4],
                                          int wave, int lane, floatx4 (&acc)[8][4]){
  constexpr int NTW  = N/64;                    // B frags per wave (disjoint cols)
  constexpr int NNTW = (NEXTN>0)? NEXTN/64 : 0;
  const int kg = lane>>4, col = lane&15;
  const int j0  = wave*(N/4);
  const int j0n = wave*(NEXTN/4);
  #pragma unroll
  for (int kk=0; kk<8; ++kk){
    if (kk < 7){
      #pragma unroll
      for (int nt=0; nt<NTW; ++nt)
        b[(kk+1)&1][nt] = *(const half8*)&Ws[(size_t)(((kk+1)*4+kg)*N + j0 + nt*16 + col)*8];
    } else if constexpr (NEXTN > 0){
      #pragma unroll
      for (int nt=0; nt<NNTW; ++nt)
        b[0][nt] = *(const half8*)&nextWs[(size_t)(kg*NEXTN + j0n + nt*16 + col)*8];
    }
    half8 a[8];
    #pragma unroll
    for (int mt=0; mt<8; ++mt)
      a[mt] = *(const half8*)(act + (size_t)(kk*4+kg)*CHS + (mt*16 + col)*16);
    __builtin_amdgcn_s_setprio(1);
    #pragma unroll
    for (int nt=0; nt<NTW; ++nt)
      #pragma unroll
      for (int mt=0; mt<8; ++mt)
        acc[mt][nt] = MFMA16(a[mt], b[kk&1][nt], acc[mt][nt]);
    __builtin_amdgcn_s_setprio(0);
  }
}

template<int NTW>
__device__ __forceinline__ void epi_relu(floatx4 (&acc)[8][4], const float* __restrict__ biasf,
                                         int boff, char* act, int wave, int lane){
  const int rg = lane>>4, col = lane&15;
  #pragma unroll
  for (int nt=0; nt<NTW; ++nt){
    int j = wave*(NTW*16) + nt*16 + col;
    float bv = biasf[boff + j];        // LDS read (lgkm) -- keeps vmcnt clean
    char* dst = act + (size_t)(j>>3)*CHS + (j&7)*2;
    #pragma unroll
    for (int mt=0; mt<8; ++mt){
      #pragma unroll
      for (int r=0; r<4; ++r){
        int e = mt*16 + rg*4 + r;
        float v = fmaxf(acc[mt][nt][r] + bv, 0.f);
        acc[mt][nt][r] = 0.f;
        *(_Float16*)(dst + (size_t)e*16) = (_Float16)v;
      }
    }
  }
}

__global__ __launch_bounds__(256,2) void msg_kernel(
    const _Float16* __restrict__ h,
    const int* __restrict__ src_csr, const int* __restrict__ dst_csr,
    const _Float16* __restrict__ W1s, const _Float16* __restrict__ W2s,
    const _Float16* __restrict__ W3s, const _Float16* __restrict__ W4s,
    const float* __restrict__ msgbias,
    _Float16* __restrict__ messages){
  __shared__ __align__(16) char smem[32*CHS + 4096];   // 69.5KB -> 2 blocks/CU
  char* act = smem;
  const float* biasf = (const float*)(smem + 32*CHS);
  const int t = threadIdx.x, wave = t>>6, lane = t&63;
  const int kg = lane>>4, col = lane&15;
  const int e0 = blockIdx.x*128;
  // stage bias concat (1024 floats; wave w loads 1KB)
  load_lds16((const char*)msgbias + wave*1024 + lane*16, smem + 32*CHS + wave*1024);
  // gather msg_in = [h[src] | h[dst]] into act chunks (0..15 src, 16..31 dst)
  {
    const int* ids = (wave < 2) ? src_csr : dst_csr;
    const int row0 = ids[e0 + lane]      * NFEAT;
    const int row1 = ids[e0 + 64 + lane] * NFEAT;
    #pragma unroll
    for (int i=0;i<8;++i){
      int c = wave*8 + i;
      int f = (c&15)*8;
      load_lds16(h + row0 + f, act + (size_t)c*CHS);
      load_lds16(h + row1 + f, act + (size_t)c*CHS + 1024);
    }
  }
  // L1 K-step-0 B prefetch (global -> regs): wave owns cols wave*64..+63
  half8 b[2][4];
  #pragma unroll
  for (int nt=0; nt<4; ++nt)
    b[0][nt] = *(const half8*)&W1s[(size_t)(kg*256 + wave*64 + nt*16 + col)*8];

  floatx4 acc[8][4];
  const floatx4 fz = {0.f,0.f,0.f,0.f};
  #pragma unroll
  for (int i=0;i<8;++i)
    #pragma unroll
    for (int j=0;j<4;++j) acc[i][j] = fz;

  WAITV0(); SBAR();                    // act + bias staged everywhere

  run_layer<256,256>(W1s, W2s, act, b, wave, lane, acc);
  WAITLGKM(); SBAR();                  // all waves' act reads done
  epi_relu<4>(acc, biasf, 0, act, wave, lane);
  WAITLGKM(); SBAR();                  // epi writes visible
  run_layer<256,256>(W2s, W3s, act, b, wave, lane, acc);
  WAITLGKM(); SBAR();
  epi_relu<4>(acc, biasf, 256, act, wave, lane);
  WAITLGKM(); SBAR();
  run_layer<256,128>(W3s, W4s, act, b, wave, lane, acc);
  WAITLGKM(); SBAR();
  epi_relu<4>(acc, biasf, 512, act, wave, lane);
  WAITLGKM(); SBAR();
  run_layer<128,0>(W4s, nullptr, act, b, wave, lane, acc);
  // L4 epilogue -> messages in CSR-slot order (contiguous rows), includes b4
  // wave owns cols wave*32..+31, all 128 edges
  {
    const int rg = lane>>4;
    #pragma unroll
    for (int nt=0; nt<2; ++nt){
      int j = wave*32 + nt*16 + col;
      float bv = biasf[768 + j];
      #pragma unroll
      for (int mt=0; mt<8; ++mt){
        #pragma unroll
        for (int r=0; r<4; ++r){
          int e = e0 + mt*16 + rg*4 + r;
          messages[(size_t)e*NEDGE + j] = (_Float16)(acc[mt][nt][r] + bv);
        }
      }
    }
  }
}

// ---------------- fused agg + GRU + output projection, 64 nodes, 8 waves ----------------
// agg: 32 slots x 16 lanes x half8 (256 B/row coalesced). Per node: fixed burst of 8
// clamped-index loads issued back-to-back (covers len<=8, ~97% of Poisson(4) rows;
// rare tail loops). If m0v != nullptr (iteration 0), messages are all the identical
// vector m0 -> agg = deg(n) * m0, no gather at all.
// h is pure-fp16 recurrent state; h_old from A2 LDS (read-before-write bijective).
__global__ __launch_bounds__(512,1) void gru_kernel(
    const _Float16* __restrict__ messages,
    const int* __restrict__ rowptr,
    const _Float16* __restrict__ nin16,
    _Float16* __restrict__ h16,
    const _Float16* __restrict__ Wihs, const _Float16* __restrict__ Whhs,
    const _Float16* __restrict__ Wfs,
    const float* __restrict__ b_ih, const float* __restrict__ b_hh,
    const float* __restrict__ b_f,
    float* __restrict__ out,
    const _Float16* __restrict__ m0v){
  __shared__ _Float16 A1[24*64*8];   // gru_in: chunks 0..15 agg, 16..23 node inputs
  __shared__ _Float16 A2[16*64*8];   // h rows (K=128); later reused for h_new
  const int t = threadIdx.x, wave = t>>6, lane = t&63;
  const int kg = lane>>4, col = lane&15;
  const int n0 = blockIdx.x*64;
  load_lds16(nin16 + (size_t)(n0+lane)*NIN + wave*8, (char*)A1 + (size_t)(16+wave)*1024);
  #pragma unroll
  for (int ii=0; ii<2; ++ii){
    int c = wave*2 + ii;
    load_lds16(h16 + (size_t)(n0+lane)*NFEAT + c*8, (char*)A2 + (size_t)c*1024);
  }
  // agg -> A1 chunks 0..15
  {
    const int slot = t>>4, chunk = t&15, l8 = (t&15)*8;  // 32 slots x 16 feat-lanes
    #pragma unroll
    for (int rr=0; rr<2; ++rr){
      const int nl = rr*32 + slot;
      const int beg = rowptr[n0 + nl], end = rowptr[n0 + nl + 1];
      float a[8] = {0.f,0.f,0.f,0.f,0.f,0.f,0.f,0.f};
      if (m0v){
        const float s = (float)(end - beg);
        #pragma unroll
        for (int q=0; q<8; ++q) a[q] = s * (float)m0v[l8+q];
      } else {
        const int len = end - beg;
        const int safe = (beg < N_EDGES) ? beg : (N_EDGES-1);
        half8 v[8];
        #pragma unroll
        for (int k=0; k<8; ++k){
          int idx = beg + k;
          idx = (idx < end) ? idx : safe;          // clamped: always a valid address
          v[k] = *(const half8*)(messages + (size_t)idx*NEDGE + l8);
        }
        #pragma unroll
        for (int k=0; k<8; ++k){
          if (k < len){
            #pragma unroll
            for (int q=0; q<8; ++q) a[q] += (float)v[k][q];
          }
        }
        for (int idx = beg+8; idx < end; ++idx){   // rare tail (len>8)
          half8 w = *(const half8*)(messages + (size_t)idx*NEDGE + l8);
          #pragma unroll
          for (int q=0; q<8; ++q) a[q] += (float)w[q];
        }
      }
      half8 o;
      #pragma unroll
      for (int q=0; q<8; ++q) o[q] = (_Float16)a[q];
      *(half8*)&A1[((size_t)chunk*64 + nl)*8] = o;
    }
  }
  floatx4 gi[3][4], gh[3][4];
  const floatx4 fz = {0.f,0.f,0.f,0.f};
  #pragma unroll
  for (int g=0; g<3; ++g)
    #pragma unroll
    for (int mt=0; mt<4; ++mt){ gi[g][mt]=fz; gh[g][mt]=fz; }

  __syncthreads();   // staging (vmcnt) + agg ds_writes (lgkm) all visible

  // wave w owns features w*16..w*16+15 (all 3 gates)
  #pragma unroll
  for (int kk=0; kk<6; ++kk){
    half8 a[4];
    #pragma unroll
    for (int mt=0;mt<4;++mt)
      a[mt] = *(const half8*)&A1[(((kk*4+kg)*64) + mt*16 + col)*8];
    #pragma unroll
    for (int g=0; g<3; ++g){
      int j = g*128 + wave*16 + col;
      half8 b = *(const half8*)&Wihs[(size_t)((kk*4+kg)*384 + j)*8];
      #pragma unroll
      for (int mt=0;mt<4;++mt)
        gi[g][mt] = MFMA16(a[mt], b, gi[g][mt]);
    }
  }
  #pragma unroll
  for (int kk=0; kk<4; ++kk){
    half8 a[4];
    #pragma unroll
    for (int mt=0;mt<4;++mt)
      a[mt] = *(const half8*)&A2[(((kk*4+kg)*64) + mt*16 + col)*8];
    #pragma unroll
    for (int g=0; g<3; ++g){
      int j = g*128 + wave*16 + col;
      half8 b = *(const half8*)&Whhs[(size_t)((kk*4+kg)*384 + j)*8];
      #pragma unroll
      for (int mt=0;mt<4;++mt)
        gh[g][mt] = MFMA16(a[mt], b, gh[g][mt]);
    }
  }
  __syncthreads();   // all A2 (h_old) MFMA reads done before overwrite

  // gates + h update; h_old from A2 LDS (read-before-write, unique slot per thread);
  // h_new -> global fp16 and back into A2 for the W_f GEMM
  {
    int jl = wave*16 + col;     // feature 0..127
    float bir=b_ih[jl], biz=b_ih[128+jl], bin_=b_ih[256+jl];
    float bhr=b_hh[jl], bhz=b_hh[128+jl], bhn=b_hh[256+jl];
    #pragma unroll
    for (int mt=0; mt<4; ++mt){
      #pragma unroll
      for (int r=0; r<4; ++r){
        int e = mt*16 + kg*4 + r;
        float ir = gi[0][mt][r] + bir;
        float iz = gi[1][mt][r] + biz;
        float inn= gi[2][mt][r] + bin_;
        float hr = gh[0][mt][r] + bhr;
        float hz = gh[1][mt][r] + bhz;
        float hn = gh[2][mt][r] + bhn;
        float rg2 = 1.f/(1.f+__expf(-(ir+hr)));
        float zg  = 1.f/(1.f+__expf(-(iz+hz)));
        float ng  = tanhf(inn + rg2*hn);
        size_t slot2 = (size_t)(((jl>>3)*64) + e)*8 + (jl&7);
        float hold = (float)A2[slot2];
        float hnew = (1.f-zg)*ng + zg*hold;
        h16[(size_t)(n0+e)*NFEAT + jl] = (_Float16)hnew;
        A2[slot2] = (_Float16)hnew;
      }
    }
  }
  __syncthreads();

  // out = h_new @ W_f^T + b_f  (K=128 -> 64 cols; waves 0..3 own 16 cols each)
  if (wave < 4){
    floatx4 facc[4];
    #pragma unroll
    for (int mt=0;mt<4;++mt) facc[mt]=fz;
    #pragma unroll
    for (int kk=0; kk<4; ++kk){
      half8 a[4];
      #pragma unroll
      for (int mt=0;mt<4;++mt)
        a[mt] = *(const half8*)&A2[(((kk*4+kg)*64) + mt*16 + col)*8];
      half8 b = *(const half8*)&Wfs[(size_t)((kk*4+kg)*64 + wave*16 + col)*8];
      #pragma unroll
      for (int mt=0;mt<4;++mt)
        facc[mt] = MFMA16(a[mt], b, facc[mt]);
    }
    float bf = b_f[wave*16+col];
    #pragma unroll
    for (int mt=0; mt<4; ++mt){
      #pragma unroll
      for (int r=0; r<4; ++r){
        int e = mt*16 + kg*4 + r;
        out[(size_t)(n0+e)*NOUTD + wave*16 + col] = facc[mt][r] + bf;
      }
    }
  }
}

// ---------------- launch ----------------
extern "C" void kernel_launch(void* const* d_in, const int* in_sizes, int n_in,
                              void* d_out, int out_size, void* d_ws, size_t ws_size,
                              hipStream_t stream){
  (void)in_sizes; (void)n_in; (void)out_size; (void)ws_size;
  const float* node_inputs = (const float*)d_in[0];
  const int*   src_ids = (const int*)d_in[1];
  const int*   dst_ids = (const int*)d_in[2];
  const float* W1 = (const float*)d_in[3];  const float* b1 = (const float*)d_in[4];
  const float* W2 = (const float*)d_in[5];  const float* b2 = (const float*)d_in[6];
  const float* W3 = (const float*)d_in[7];  const float* b3 = (const float*)d_in[8];
  const float* W4 = (const float*)d_in[9];  const float* b4 = (const float*)d_in[10];
  const float* W_ih = (const float*)d_in[11];
  const float* W_hh = (const float*)d_in[12];
  const float* b_ih = (const float*)d_in[13];
  const float* b_hh = (const float*)d_in[14];
  const float* W_f  = (const float*)d_in[15];
  const float* b_f  = (const float*)d_in[16];
  float* out = (float*)d_out;

  char* ws = (char*)d_ws;
  auto alloc = [&](size_t b){ char* p = ws; ws += (b + 255) & ~(size_t)255; return p; };
  _Float16* h16  = (_Float16*)alloc((size_t)N_NODES*NFEAT*2);
  _Float16* nin16= (_Float16*)alloc((size_t)N_NODES*NIN*2);
  _Float16* msgs = (_Float16*)alloc((size_t)N_EDGES*NEDGE*2);
  _Float16* W1s  = (_Float16*)alloc(256*256*2);
  _Float16* W2s  = (_Float16*)alloc(256*256*2);
  _Float16* W3s  = (_Float16*)alloc(256*256*2);
  _Float16* W4s  = (_Float16*)alloc(128*256*2);
  _Float16* Wihs = (_Float16*)alloc(384*192*2);
  _Float16* Whhs = (_Float16*)alloc(384*128*2);
  _Float16* Wfs  = (_Float16*)alloc(64*128*2);
  float* msgbias = (float*)alloc(1024*4);
  _Float16* m0   = (_Float16*)alloc(128*2);
  int* cnt     = (int*)alloc((size_t)N_NODES*4);
  int* rowptr  = (int*)alloc((size_t)(N_NODES+1)*4);
  int* offs    = (int*)alloc((size_t)N_NODES*4);
  int* src_csr = (int*)alloc((size_t)N_EDGES*4);
  int* dst_csr = (int*)alloc((size_t)N_EDGES*4);

  setup_kernel<<<8192+4096+64+176+4,256,0,stream>>>(
      node_inputs, W1,W2,W3,W4, W_ih,W_hh,W_f, b1,b2,b3,b4,
      h16, nin16, W1s,W2s,W3s,W4s, Wihs,Whhs,Wfs, msgbias, cnt);
  mlp0_kernel<<<1,256,0,stream>>>(W2, W3, W4, b1, b2, b3, b4, m0);
  hist_kernel<<<N_EDGES/256,256,0,stream>>>(dst_ids, cnt);
  scan_kernel<<<1,1024,0,stream>>>(cnt, rowptr, offs);
  scatter_kernel<<<N_EDGES/256,256,0,stream>>>(src_ids, dst_ids, offs, src_csr, dst_csr);

  // iteration 0: h0==0 -> messages are all m0; skip msg_kernel entirely
  gru_kernel<<<N_NODES/64,512,0,stream>>>(msgs, rowptr, nin16, h16,
                                          Wihs, Whhs, Wfs, b_ih, b_hh, b_f,
                                          out, m0);
  for (int it=1; it<NITERS; ++it){
    msg_kernel<<<N_EDGES/128,256,0,stream>>>(h16, src_csr, dst_csr,
                                             W1s,W2s,W3s,W4s, msgbias, msgs);
    gru_kernel<<<N_NODES/64,512,0,stream>>>(msgs, rowptr, nin16, h16,
                                            Wihs, Whhs, Wfs, b_ih, b_hh, b_f,
                                            out + (size_t)it*N_NODES*NOUTD, nullptr);
  }
}

// Round 19
// 366.707 us; speedup vs baseline: 1.2233x; 1.0044x over previous
//
#include <hip/hip_runtime.h>
#include <cstdint>
#include <cstddef>

#define N_NODES 16384
#define N_EDGES 65536
#define NFEAT 128   // GRU hidden
#define NIN   64    // node inputs
#define NEDGE 128   // edge features
#define NOUTD 64    // node outputs
#define NITERS 7

#define CHS 2080    // act chunk stride bytes (128 edges * 16B + 32B pad)

typedef _Float16 half8 __attribute__((ext_vector_type(8)));
typedef _Float16 half4 __attribute__((ext_vector_type(4)));
typedef float floatx4 __attribute__((ext_vector_type(4)));

#define MFMA16(a,b,c) __builtin_amdgcn_mfma_f32_16x16x32_f16((a),(b),(c),0,0,0)

// raw barrier (no vmcnt(0) drain, unlike __syncthreads)
#define SBAR() asm volatile("s_barrier" ::: "memory")
#define WAITLGKM() asm volatile("s_waitcnt lgkmcnt(0)" ::: "memory")
#define WAITV0() asm volatile("s_waitcnt vmcnt(0)" ::: "memory")

// async global->LDS, 16B per lane. Global src per-lane; LDS dest wave-uniform base (+lane*16 by HW).
__device__ __forceinline__ void load_lds16(const void* g, void* l){
  __builtin_amdgcn_global_load_lds(
      (__attribute__((address_space(1))) void*)(uintptr_t)g,
      (__attribute__((address_space(3))) void*)l,
      16, 0, 0);
}

// ---------------- one-shot setup: nin cvt + fp16 weight repack + bias concat ----------------
// h16 needs NO init: gru0 (h0==0 path) writes every element before any reader.
// repack: W (NOUT x KIN) f32 row-major -> [KIN/8][NOUT][8] f16
__global__ void setup_kernel(
    const float* __restrict__ node_inputs,
    const float* __restrict__ W1, const float* __restrict__ W2,
    const float* __restrict__ W3, const float* __restrict__ W4,
    const float* __restrict__ W_ih, const float* __restrict__ W_hh,
    const float* __restrict__ W_f,
    const float* __restrict__ b1, const float* __restrict__ b2,
    const float* __restrict__ b3, const float* __restrict__ b4,
    _Float16* __restrict__ nin16,
    _Float16* __restrict__ W1s, _Float16* __restrict__ W2s, _Float16* __restrict__ W3s,
    _Float16* __restrict__ W4s, _Float16* __restrict__ Wihs, _Float16* __restrict__ Whhs,
    _Float16* __restrict__ Wfs, float* __restrict__ msgbias, int* __restrict__ cnt){
  int b = blockIdx.x, t = threadIdx.x;
  if (b < 4096){ int i=b*256+t; nin16[i] = (_Float16)node_inputs[i]; return; }
  b -= 4096;
  if (b < 64){ cnt[b*256+t] = 0; return; }
  b -= 64;
  if (b >= 176){  // bias concat: b1|b2|b3|b4 -> msgbias[1024] (zero-padded)
    int i = (b-176)*256 + t;
    float v = 0.f;
    if      (i < 256) v = b1[i];
    else if (i < 512) v = b2[i-256];
    else if (i < 768) v = b3[i-512];
    else if (i < 896) v = b4[i-768];
    msgbias[i] = v; return;
  }
  const float* W; _Float16* o; int NO, KI, base;
  if      (b < 32){ W=W1;  o=W1s;  NO=256; KI=256; base=b; }
  else if (b < 64){ W=W2;  o=W2s;  NO=256; KI=256; base=b-32; }
  else if (b < 96){ W=W3;  o=W3s;  NO=256; KI=256; base=b-64; }
  else if (b <112){ W=W4;  o=W4s;  NO=128; KI=256; base=b-96; }
  else if (b <148){ W=W_ih;o=Wihs; NO=384; KI=192; base=b-112; }
  else if (b <172){ W=W_hh;o=Whhs; NO=384; KI=128; base=b-148; }
  else            { W=W_f; o=Wfs;  NO=64;  KI=128; base=b-172; }
  int g = base*256 + t;
  int total = NO*(KI>>3);
  if (g >= total) return;
  int c = g/NO, j = g - c*NO;
  #pragma unroll
  for (int i=0;i<8;++i) o[(size_t)g*8+i] = (_Float16)W[(size_t)j*KI + c*8 + i];
}

__global__ void hist_kernel(const int* __restrict__ dst, int* __restrict__ cnt){
  int e = blockIdx.x*256+threadIdx.x; if (e<N_EDGES) atomicAdd(&cnt[dst[e]],1);
}

// block 0: exclusive scan of cnt -> rowptr/offs.  block 1: mlp0 (iteration-0
// shortcut: h0==0 -> every message is m0 = bias-only MLP chain, fp32).
__global__ __launch_bounds__(1024) void scan_kernel(const int* __restrict__ cnt,
                                                    int* __restrict__ rowptr,
                                                    int* __restrict__ offs,
                                                    const float* __restrict__ W2,
                                                    const float* __restrict__ W3,
                                                    const float* __restrict__ W4,
                                                    const float* __restrict__ b1,
                                                    const float* __restrict__ b2,
                                                    const float* __restrict__ b3,
                                                    const float* __restrict__ b4,
                                                    _Float16* __restrict__ m0){
  int t = threadIdx.x;
  if (blockIdx.x == 1){
    __shared__ float x1[256], x2[256], x3[256];
    if (t < 256) x1[t] = fmaxf(b1[t], 0.f);
    __syncthreads();
    if (t < 256){
      float s = b2[t];
      for (int k=0;k<256;++k) s += W2[(size_t)t*256+k]*x1[k];
      x2[t] = fmaxf(s, 0.f);
    }
    __syncthreads();
    if (t < 256){
      float s = b3[t];
      for (int k=0;k<256;++k) s += W3[(size_t)t*256+k]*x2[k];
      x3[t] = fmaxf(s, 0.f);
    }
    __syncthreads();
    if (t < 128){
      float s = b4[t];
      for (int k=0;k<256;++k) s += W4[(size_t)t*256+k]*x3[k];
      m0[t] = (_Float16)s;
    }
    return;
  }
  __shared__ int sd[1024];
  int c[16]; int s=0;
  #pragma unroll
  for (int k=0;k<16;++k){ c[k]=cnt[t*16+k]; s+=c[k]; }
  sd[t]=s; __syncthreads();
  for (int off=1; off<1024; off<<=1){
    int v = (t>=off)? sd[t-off]:0;
    __syncthreads();
    sd[t]+=v;
    __syncthreads();
  }
  int base = sd[t]-s; // exclusive prefix
  #pragma unroll
  for (int k=0;k<16;++k){ rowptr[t*16+k]=base; offs[t*16+k]=base; base+=c[k]; }
  if (t==0) rowptr[N_NODES]=N_EDGES;
}
// CSR permutation: src/dst ids in CSR-slot order -> msg writes message rows
// contiguously in dst-grouped order (agg reads sequentially).
__global__ void scatter_kernel(const int* __restrict__ src, const int* __restrict__ dst,
                               int* __restrict__ offs,
                               int* __restrict__ src_csr, int* __restrict__ dst_csr){
  int e = blockIdx.x*256+threadIdx.x;
  if (e<N_EDGES){
    int d = dst[e];
    int p = atomicAdd(&offs[d],1);
    src_csr[p] = src[e];
    dst_csr[p] = d;
  }
}

// ---------------- fused 4-layer edge MLP: 128 edges/block, 4 waves, 2 blocks/CU --------
// act LDS: [32 chunks][128 edges][8 halfs], chunk stride CHS (padded).
// Wave grid = 1M x 4N: each wave owns ALL 128 edges x N/4 cols, so B fragments are
// DISJOINT across waves. B frags: global(L2) -> VGPR, double-buffered one K-step
// ahead. No in-loop barriers.
template<int N, int NEXTN>
__device__ __forceinline__ void run_layer(const _Float16* __restrict__ Ws,
                                          const _Float16* __restrict__ nextWs,
                                          const char* act, half8 (&b)[2][4],
                                          int wave, int lane, floatx4 (&acc)[8][4]){
  constexpr int NTW  = N/64;                    // B frags per wave (disjoint cols)
  constexpr int NNTW = (NEXTN>0)? NEXTN/64 : 0;
  const int kg = lane>>4, col = lane&15;
  const int j0  = wave*(N/4);
  const int j0n = wave*(NEXTN/4);
  #pragma unroll
  for (int kk=0; kk<8; ++kk){
    if (kk < 7){
      #pragma unroll
      for (int nt=0; nt<NTW; ++nt)
        b[(kk+1)&1][nt] = *(const half8*)&Ws[(size_t)(((kk+1)*4+kg)*N + j0 + nt*16 + col)*8];
    } else if constexpr (NEXTN > 0){
      #pragma unroll
      for (int nt=0; nt<NNTW; ++nt)
        b[0][nt] = *(const half8*)&nextWs[(size_t)(kg*NEXTN + j0n + nt*16 + col)*8];
    }
    half8 a[8];
    #pragma unroll
    for (int mt=0; mt<8; ++mt)
      a[mt] = *(const half8*)(act + (size_t)(kk*4+kg)*CHS + (mt*16 + col)*16);
    __builtin_amdgcn_s_setprio(1);
    #pragma unroll
    for (int nt=0; nt<NTW; ++nt)
      #pragma unroll
      for (int mt=0; mt<8; ++mt)
        acc[mt][nt] = MFMA16(a[mt], b[kk&1][nt], acc[mt][nt]);
    __builtin_amdgcn_s_setprio(0);
  }
}

template<int NTW>
__device__ __forceinline__ void epi_relu(floatx4 (&acc)[8][4], const float* __restrict__ biasf,
                                         int boff, char* act, int wave, int lane){
  const int rg = lane>>4, col = lane&15;
  #pragma unroll
  for (int nt=0; nt<NTW; ++nt){
    int j = wave*(NTW*16) + nt*16 + col;
    float bv = biasf[boff + j];        // LDS read (lgkm) -- keeps vmcnt clean
    char* dst = act + (size_t)(j>>3)*CHS + (j&7)*2;
    #pragma unroll
    for (int mt=0; mt<8; ++mt){
      #pragma unroll
      for (int r=0; r<4; ++r){
        int e = mt*16 + rg*4 + r;
        float v = fmaxf(acc[mt][nt][r] + bv, 0.f);
        acc[mt][nt][r] = 0.f;
        *(_Float16*)(dst + (size_t)e*16) = (_Float16)v;
      }
    }
  }
}

__global__ __launch_bounds__(256,2) void msg_kernel(
    const _Float16* __restrict__ h,
    const int* __restrict__ src_csr, const int* __restrict__ dst_csr,
    const _Float16* __restrict__ W1s, const _Float16* __restrict__ W2s,
    const _Float16* __restrict__ W3s, const _Float16* __restrict__ W4s,
    const float* __restrict__ msgbias,
    _Float16* __restrict__ messages){
  __shared__ __align__(16) char smem[32*CHS + 4096];   // 69.5KB -> 2 blocks/CU
  char* act = smem;
  const float* biasf = (const float*)(smem + 32*CHS);
  const int t = threadIdx.x, wave = t>>6, lane = t&63;
  const int kg = lane>>4, col = lane&15;
  const int e0 = blockIdx.x*128;
  // stage bias concat (1024 floats; wave w loads 1KB)
  load_lds16((const char*)msgbias + wave*1024 + lane*16, smem + 32*CHS + wave*1024);
  // gather msg_in = [h[src] | h[dst]] into act chunks (0..15 src, 16..31 dst)
  {
    const int* ids = (wave < 2) ? src_csr : dst_csr;
    const int row0 = ids[e0 + lane]      * NFEAT;
    const int row1 = ids[e0 + 64 + lane] * NFEAT;
    #pragma unroll
    for (int i=0;i<8;++i){
      int c = wave*8 + i;
      int f = (c&15)*8;
      load_lds16(h + row0 + f, act + (size_t)c*CHS);
      load_lds16(h + row1 + f, act + (size_t)c*CHS + 1024);
    }
  }
  // L1 K-step-0 B prefetch (global -> regs): wave owns cols wave*64..+63
  half8 b[2][4];
  #pragma unroll
  for (int nt=0; nt<4; ++nt)
    b[0][nt] = *(const half8*)&W1s[(size_t)(kg*256 + wave*64 + nt*16 + col)*8];

  floatx4 acc[8][4];
  const floatx4 fz = {0.f,0.f,0.f,0.f};
  #pragma unroll
  for (int i=0;i<8;++i)
    #pragma unroll
    for (int j=0;j<4;++j) acc[i][j] = fz;

  WAITV0(); SBAR();                    // act + bias staged everywhere

  run_layer<256,256>(W1s, W2s, act, b, wave, lane, acc);
  WAITLGKM(); SBAR();                  // all waves' act reads done
  epi_relu<4>(acc, biasf, 0, act, wave, lane);
  WAITLGKM(); SBAR();                  // epi writes visible
  run_layer<256,256>(W2s, W3s, act, b, wave, lane, acc);
  WAITLGKM(); SBAR();
  epi_relu<4>(acc, biasf, 256, act, wave, lane);
  WAITLGKM(); SBAR();
  run_layer<256,128>(W3s, W4s, act, b, wave, lane, acc);
  WAITLGKM(); SBAR();
  epi_relu<4>(acc, biasf, 512, act, wave, lane);
  WAITLGKM(); SBAR();
  run_layer<128,0>(W4s, nullptr, act, b, wave, lane, acc);
  // L4 epilogue -> messages in CSR-slot order (contiguous rows), includes b4
  // wave owns cols wave*32..+31, all 128 edges
  {
    const int rg = lane>>4;
    #pragma unroll
    for (int nt=0; nt<2; ++nt){
      int j = wave*32 + nt*16 + col;
      float bv = biasf[768 + j];
      #pragma unroll
      for (int mt=0; mt<8; ++mt){
        #pragma unroll
        for (int r=0; r<4; ++r){
          int e = e0 + mt*16 + rg*4 + r;
          messages[(size_t)e*NEDGE + j] = (_Float16)(acc[mt][nt][r] + bv);
        }
      }
    }
  }
}

// ---------------- fused agg + GRU + output projection, 64 nodes, 8 waves ----------------
// agg: 32 slots x 16 lanes x half8 (256 B/row coalesced). Per node: fixed burst of 8
// clamped-index loads issued back-to-back (len<=8 covers ~97%; rare tail loops).
// If m0v != nullptr (iteration 0, h0==0): agg = deg(n)*m0, gh == 0, h_old == 0 --
// no h16 read/staging at all (h16 is write-only here, defined for iteration 1).
// h is pure-fp16 recurrent state; h_old from A2 LDS (read-before-write bijective).
__global__ __launch_bounds__(512,1) void gru_kernel(
    const _Float16* __restrict__ messages,
    const int* __restrict__ rowptr,
    const _Float16* __restrict__ nin16,
    _Float16* __restrict__ h16,
    const _Float16* __restrict__ Wihs, const _Float16* __restrict__ Whhs,
    const _Float16* __restrict__ Wfs,
    const float* __restrict__ b_ih, const float* __restrict__ b_hh,
    const float* __restrict__ b_f,
    float* __restrict__ out,
    const _Float16* __restrict__ m0v){
  __shared__ _Float16 A1[24*64*8];   // gru_in: chunks 0..15 agg, 16..23 node inputs
  __shared__ _Float16 A2[16*64*8];   // h rows (K=128); later reused for h_new
  const int t = threadIdx.x, wave = t>>6, lane = t&63;
  const int kg = lane>>4, col = lane&15;
  const int n0 = blockIdx.x*64;
  load_lds16(nin16 + (size_t)(n0+lane)*NIN + wave*8, (char*)A1 + (size_t)(16+wave)*1024);
  if (!m0v){
    #pragma unroll
    for (int ii=0; ii<2; ++ii){
      int c = wave*2 + ii;
      load_lds16(h16 + (size_t)(n0+lane)*NFEAT + c*8, (char*)A2 + (size_t)c*1024);
    }
  }
  // agg -> A1 chunks 0..15
  {
    const int slot = t>>4, chunk = t&15, l8 = (t&15)*8;  // 32 slots x 16 feat-lanes
    #pragma unroll
    for (int rr=0; rr<2; ++rr){
      const int nl = rr*32 + slot;
      const int beg = rowptr[n0 + nl], end = rowptr[n0 + nl + 1];
      float a[8] = {0.f,0.f,0.f,0.f,0.f,0.f,0.f,0.f};
      if (m0v){
        const float s = (float)(end - beg);
        #pragma unroll
        for (int q=0; q<8; ++q) a[q] = s * (float)m0v[l8+q];
      } else {
        const int len = end - beg;
        const int safe = (beg < N_EDGES) ? beg : (N_EDGES-1);
        half8 v[8];
        #pragma unroll
        for (int k=0; k<8; ++k){
          int idx = beg + k;
          idx = (idx < end) ? idx : safe;          // clamped: always a valid address
          v[k] = *(const half8*)(messages + (size_t)idx*NEDGE + l8);
        }
        #pragma unroll
        for (int k=0; k<8; ++k){
          if (k < len){
            #pragma unroll
            for (int q=0; q<8; ++q) a[q] += (float)v[k][q];
          }
        }
        for (int idx = beg+8; idx < end; ++idx){   // rare tail (len>8)
          half8 w = *(const half8*)(messages + (size_t)idx*NEDGE + l8);
          #pragma unroll
          for (int q=0; q<8; ++q) a[q] += (float)w[q];
        }
      }
      half8 o;
      #pragma unroll
      for (int q=0; q<8; ++q) o[q] = (_Float16)a[q];
      *(half8*)&A1[((size_t)chunk*64 + nl)*8] = o;
    }
  }
  floatx4 gi[3][4], gh[3][4];
  const floatx4 fz = {0.f,0.f,0.f,0.f};
  #pragma unroll
  for (int g=0; g<3; ++g)
    #pragma unroll
    for (int mt=0; mt<4; ++mt){ gi[g][mt]=fz; gh[g][mt]=fz; }

  __syncthreads();   // staging (vmcnt) + agg ds_writes (lgkm) all visible

  // wave w owns features w*16..w*16+15 (all 3 gates)
  #pragma unroll
  for (int kk=0; kk<6; ++kk){
    half8 a[4];
    #pragma unroll
    for (int mt=0;mt<4;++mt)
      a[mt] = *(const half8*)&A1[(((kk*4+kg)*64) + mt*16 + col)*8];
    #pragma unroll
    for (int g=0; g<3; ++g){
      int j = g*128 + wave*16 + col;
      half8 b = *(const half8*)&Wihs[(size_t)((kk*4+kg)*384 + j)*8];
      #pragma unroll
      for (int mt=0;mt<4;++mt)
        gi[g][mt] = MFMA16(a[mt], b, gi[g][mt]);
    }
  }
  if (!m0v){
    #pragma unroll
    for (int kk=0; kk<4; ++kk){
      half8 a[4];
      #pragma unroll
      for (int mt=0;mt<4;++mt)
        a[mt] = *(const half8*)&A2[(((kk*4+kg)*64) + mt*16 + col)*8];
      #pragma unroll
      for (int g=0; g<3; ++g){
        int j = g*128 + wave*16 + col;
        half8 b = *(const half8*)&Whhs[(size_t)((kk*4+kg)*384 + j)*8];
        #pragma unroll
        for (int mt=0;mt<4;++mt)
          gh[g][mt] = MFMA16(a[mt], b, gh[g][mt]);
      }
    }
  }
  __syncthreads();   // all A2 (h_old) MFMA reads done before overwrite

  // gates + h update; h_old from A2 LDS (read-before-write, unique slot per thread);
  // h_new -> global fp16 and back into A2 for the W_f GEMM
  {
    int jl = wave*16 + col;     // feature 0..127
    float bir=b_ih[jl], biz=b_ih[128+jl], bin_=b_ih[256+jl];
    float bhr=b_hh[jl], bhz=b_hh[128+jl], bhn=b_hh[256+jl];
    #pragma unroll
    for (int mt=0; mt<4; ++mt){
      #pragma unroll
      for (int r=0; r<4; ++r){
        int e = mt*16 + kg*4 + r;
        float ir = gi[0][mt][r] + bir;
        float iz = gi[1][mt][r] + biz;
        float inn= gi[2][mt][r] + bin_;
        float hr = gh[0][mt][r] + bhr;
        float hz = gh[1][mt][r] + bhz;
        float hn = gh[2][mt][r] + bhn;
        float rg2 = 1.f/(1.f+__expf(-(ir+hr)));
        float zg  = 1.f/(1.f+__expf(-(iz+hz)));
        float ng  = tanhf(inn + rg2*hn);
        size_t slot2 = (size_t)(((jl>>3)*64) + e)*8 + (jl&7);
        float hold = m0v ? 0.f : (float)A2[slot2];
        float hnew = (1.f-zg)*ng + zg*hold;
        h16[(size_t)(n0+e)*NFEAT + jl] = (_Float16)hnew;
        A2[slot2] = (_Float16)hnew;
      }
    }
  }
  __syncthreads();

  // out = h_new @ W_f^T + b_f  (K=128 -> 64 cols; waves 0..3 own 16 cols each)
  if (wave < 4){
    floatx4 facc[4];
    #pragma unroll
    for (int mt=0;mt<4;++mt) facc[mt]=fz;
    #pragma unroll
    for (int kk=0; kk<4; ++kk){
      half8 a[4];
      #pragma unroll
      for (int mt=0;mt<4;++mt)
        a[mt] = *(const half8*)&A2[(((kk*4+kg)*64) + mt*16 + col)*8];
      half8 b = *(const half8*)&Wfs[(size_t)((kk*4+kg)*64 + wave*16 + col)*8];
      #pragma unroll
      for (int mt=0;mt<4;++mt)
        facc[mt] = MFMA16(a[mt], b, facc[mt]);
    }
    float bf = b_f[wave*16+col];
    #pragma unroll
    for (int mt=0; mt<4; ++mt){
      #pragma unroll
      for (int r=0; r<4; ++r){
        int e = mt*16 + kg*4 + r;
        out[(size_t)(n0+e)*NOUTD + wave*16 + col] = facc[mt][r] + bf;
      }
    }
  }
}

// ---------------- launch ----------------
extern "C" void kernel_launch(void* const* d_in, const int* in_sizes, int n_in,
                              void* d_out, int out_size, void* d_ws, size_t ws_size,
                              hipStream_t stream){
  (void)in_sizes; (void)n_in; (void)out_size; (void)ws_size;
  const float* node_inputs = (const float*)d_in[0];
  const int*   src_ids = (const int*)d_in[1];
  const int*   dst_ids = (const int*)d_in[2];
  const float* W1 = (const float*)d_in[3];  const float* b1 = (const float*)d_in[4];
  const float* W2 = (const float*)d_in[5];  const float* b2 = (const float*)d_in[6];
  const float* W3 = (const float*)d_in[7];  const float* b3 = (const float*)d_in[8];
  const float* W4 = (const float*)d_in[9];  const float* b4 = (const float*)d_in[10];
  const float* W_ih = (const float*)d_in[11];
  const float* W_hh = (const float*)d_in[12];
  const float* b_ih = (const float*)d_in[13];
  const float* b_hh = (const float*)d_in[14];
  const float* W_f  = (const float*)d_in[15];
  const float* b_f  = (const float*)d_in[16];
  float* out = (float*)d_out;

  char* ws = (char*)d_ws;
  auto alloc = [&](size_t b){ char* p = ws; ws += (b + 255) & ~(size_t)255; return p; };
  _Float16* h16  = (_Float16*)alloc((size_t)N_NODES*NFEAT*2);
  _Float16* nin16= (_Float16*)alloc((size_t)N_NODES*NIN*2);
  _Float16* msgs = (_Float16*)alloc((size_t)N_EDGES*NEDGE*2);
  _Float16* W1s  = (_Float16*)alloc(256*256*2);
  _Float16* W2s  = (_Float16*)alloc(256*256*2);
  _Float16* W3s  = (_Float16*)alloc(256*256*2);
  _Float16* W4s  = (_Float16*)alloc(128*256*2);
  _Float16* Wihs = (_Float16*)alloc(384*192*2);
  _Float16* Whhs = (_Float16*)alloc(384*128*2);
  _Float16* Wfs  = (_Float16*)alloc(64*128*2);
  float* msgbias = (float*)alloc(1024*4);
  _Float16* m0   = (_Float16*)alloc(128*2);
  int* cnt     = (int*)alloc((size_t)N_NODES*4);
  int* rowptr  = (int*)alloc((size_t)(N_NODES+1)*4);
  int* offs    = (int*)alloc((size_t)N_NODES*4);
  int* src_csr = (int*)alloc((size_t)N_EDGES*4);
  int* dst_csr = (int*)alloc((size_t)N_EDGES*4);

  setup_kernel<<<4096+64+176+4,256,0,stream>>>(
      node_inputs, W1,W2,W3,W4, W_ih,W_hh,W_f, b1,b2,b3,b4,
      nin16, W1s,W2s,W3s,W4s, Wihs,Whhs,Wfs, msgbias, cnt);
  hist_kernel<<<N_EDGES/256,256,0,stream>>>(dst_ids, cnt);
  scan_kernel<<<2,1024,0,stream>>>(cnt, rowptr, offs, W2, W3, W4, b1, b2, b3, b4, m0);
  scatter_kernel<<<N_EDGES/256,256,0,stream>>>(src_ids, dst_ids, offs, src_csr, dst_csr);

  // iteration 0: h0==0 -> messages are all m0; skip msg_kernel, gh==0, no h16 read
  gru_kernel<<<N_NODES/64,512,0,stream>>>(msgs, rowptr, nin16, h16,
                                          Wihs, Whhs, Wfs, b_ih, b_hh, b_f,
                                          out, m0);
  for (int it=1; it<NITERS; ++it){
    msg_kernel<<<N_EDGES/128,256,0,stream>>>(h16, src_csr, dst_csr,
                                             W1s,W2s,W3s,W4s, msgbias, msgs);
    gru_kernel<<<N_NODES/64,512,0,stream>>>(msgs, rowptr, nin16, h16,
                                            Wihs, Whhs, Wfs, b_ih, b_hh, b_f,
                                            out + (size_t)it*N_NODES*NOUTD, nullptr);
  }
}

// Round 20
// 361.648 us; speedup vs baseline: 1.2404x; 1.0140x over previous
//
#include <hip/hip_runtime.h>
#include <cstdint>
#include <cstddef>

#define N_NODES 16384
#define N_EDGES 65536
#define NFEAT 128   // GRU hidden
#define NIN   64    // node inputs
#define NEDGE 128   // edge features
#define NOUTD 64    // node outputs
#define NITERS 7

#define CHS 2080    // act chunk stride bytes (128 edges * 16B + 32B pad)

typedef _Float16 half8 __attribute__((ext_vector_type(8)));
typedef _Float16 half4 __attribute__((ext_vector_type(4)));
typedef float floatx4 __attribute__((ext_vector_type(4)));

#define MFMA16(a,b,c) __builtin_amdgcn_mfma_f32_16x16x32_f16((a),(b),(c),0,0,0)

// raw barrier (no vmcnt(0) drain, unlike __syncthreads)
#define SBAR() asm volatile("s_barrier" ::: "memory")
#define WAITLGKM() asm volatile("s_waitcnt lgkmcnt(0)" ::: "memory")
#define WAITV0() asm volatile("s_waitcnt vmcnt(0)" ::: "memory")

// async global->LDS, 16B per lane. Global src per-lane; LDS dest wave-uniform base (+lane*16 by HW).
__device__ __forceinline__ void load_lds16(const void* g, void* l){
  __builtin_amdgcn_global_load_lds(
      (__attribute__((address_space(1))) void*)(uintptr_t)g,
      (__attribute__((address_space(3))) void*)l,
      16, 0, 0);
}

// ---------------- one-shot setup: nin cvt + fp16 weight repack + bias concat ----------------
// h16 needs NO init: gru0 (h0==0 path) writes every element before any reader.
// repack: W (NOUT x KIN) f32 row-major -> [KIN/8][NOUT][8] f16
__global__ void setup_kernel(
    const float* __restrict__ node_inputs,
    const float* __restrict__ W1, const float* __restrict__ W2,
    const float* __restrict__ W3, const float* __restrict__ W4,
    const float* __restrict__ W_ih, const float* __restrict__ W_hh,
    const float* __restrict__ W_f,
    const float* __restrict__ b1, const float* __restrict__ b2,
    const float* __restrict__ b3, const float* __restrict__ b4,
    _Float16* __restrict__ nin16,
    _Float16* __restrict__ W1s, _Float16* __restrict__ W2s, _Float16* __restrict__ W3s,
    _Float16* __restrict__ W4s, _Float16* __restrict__ Wihs, _Float16* __restrict__ Whhs,
    _Float16* __restrict__ Wfs, float* __restrict__ msgbias, int* __restrict__ cnt){
  int b = blockIdx.x, t = threadIdx.x;
  if (b < 4096){ int i=b*256+t; nin16[i] = (_Float16)node_inputs[i]; return; }
  b -= 4096;
  if (b < 64){ cnt[b*256+t] = 0; return; }
  b -= 64;
  if (b >= 176){  // bias concat: b1|b2|b3|b4 -> msgbias[1024] (zero-padded)
    int i = (b-176)*256 + t;
    float v = 0.f;
    if      (i < 256) v = b1[i];
    else if (i < 512) v = b2[i-256];
    else if (i < 768) v = b3[i-512];
    else if (i < 896) v = b4[i-768];
    msgbias[i] = v; return;
  }
  const float* W; _Float16* o; int NO, KI, base;
  if      (b < 32){ W=W1;  o=W1s;  NO=256; KI=256; base=b; }
  else if (b < 64){ W=W2;  o=W2s;  NO=256; KI=256; base=b-32; }
  else if (b < 96){ W=W3;  o=W3s;  NO=256; KI=256; base=b-64; }
  else if (b <112){ W=W4;  o=W4s;  NO=128; KI=256; base=b-96; }
  else if (b <148){ W=W_ih;o=Wihs; NO=384; KI=192; base=b-112; }
  else if (b <172){ W=W_hh;o=Whhs; NO=384; KI=128; base=b-148; }
  else            { W=W_f; o=Wfs;  NO=64;  KI=128; base=b-172; }
  int g = base*256 + t;
  int total = NO*(KI>>3);
  if (g >= total) return;
  int c = g/NO, j = g - c*NO;
  #pragma unroll
  for (int i=0;i<8;++i) o[(size_t)g*8+i] = (_Float16)W[(size_t)j*KI + c*8 + i];
}

__global__ void hist_kernel(const int* __restrict__ dst, int* __restrict__ cnt){
  int e = blockIdx.x*256+threadIdx.x; if (e<N_EDGES) atomicAdd(&cnt[dst[e]],1);
}

// block 0: exclusive scan of cnt -> rowptr/offs.  block 1: mlp0 (iteration-0
// shortcut: h0==0 -> every message is m0 = bias-only MLP chain, fp32).
__global__ __launch_bounds__(1024) void scan_kernel(const int* __restrict__ cnt,
                                                    int* __restrict__ rowptr,
                                                    int* __restrict__ offs,
                                                    const float* __restrict__ W2,
                                                    const float* __restrict__ W3,
                                                    const float* __restrict__ W4,
                                                    const float* __restrict__ b1,
                                                    const float* __restrict__ b2,
                                                    const float* __restrict__ b3,
                                                    const float* __restrict__ b4,
                                                    _Float16* __restrict__ m0){
  int t = threadIdx.x;
  if (blockIdx.x == 1){
    __shared__ float x1[256], x2[256], x3[256];
    if (t < 256) x1[t] = fmaxf(b1[t], 0.f);
    __syncthreads();
    if (t < 256){
      float s = b2[t];
      for (int k=0;k<256;++k) s += W2[(size_t)t*256+k]*x1[k];
      x2[t] = fmaxf(s, 0.f);
    }
    __syncthreads();
    if (t < 256){
      float s = b3[t];
      for (int k=0;k<256;++k) s += W3[(size_t)t*256+k]*x2[k];
      x3[t] = fmaxf(s, 0.f);
    }
    __syncthreads();
    if (t < 128){
      float s = b4[t];
      for (int k=0;k<256;++k) s += W4[(size_t)t*256+k]*x3[k];
      m0[t] = (_Float16)s;
    }
    return;
  }
  __shared__ int sd[1024];
  int c[16]; int s=0;
  #pragma unroll
  for (int k=0;k<16;++k){ c[k]=cnt[t*16+k]; s+=c[k]; }
  sd[t]=s; __syncthreads();
  for (int off=1; off<1024; off<<=1){
    int v = (t>=off)? sd[t-off]:0;
    __syncthreads();
    sd[t]+=v;
    __syncthreads();
  }
  int base = sd[t]-s; // exclusive prefix
  #pragma unroll
  for (int k=0;k<16;++k){ rowptr[t*16+k]=base; offs[t*16+k]=base; base+=c[k]; }
  if (t==0) rowptr[N_NODES]=N_EDGES;
}
// CSR permutation: src/dst ids in CSR-slot order -> msg writes message rows
// contiguously in dst-grouped order (agg reads sequentially).
__global__ void scatter_kernel(const int* __restrict__ src, const int* __restrict__ dst,
                               int* __restrict__ offs,
                               int* __restrict__ src_csr, int* __restrict__ dst_csr){
  int e = blockIdx.x*256+threadIdx.x;
  if (e<N_EDGES){
    int d = dst[e];
    int p = atomicAdd(&offs[d],1);
    src_csr[p] = src[e];
    dst_csr[p] = d;
  }
}

// ---------------- fused 4-layer edge MLP: 128 edges/block, 4 waves, 2 blocks/CU --------
// act LDS: [32 chunks][128 edges][8 halfs], chunk stride CHS (padded).
// TRANSPOSED-C scheme: compute D = W x X (operands swapped vs classic X W^T), so
// each lane's 4 C-regs are 4 CONSECUTIVE FEATURES of one edge -> vector ds_write_b64
// epilogue (was 128 scalar b16 stores/lane with 8-way bank conflicts).
// Wave w owns output features w*(N/4)..+N/4 (W frags disjoint across waves, from L2,
// double-buffered one K-step ahead); act frags (all 128 edges) from LDS. No in-loop barriers.
template<int N, int NEXTN>
__device__ __forceinline__ void run_layer(const _Float16* __restrict__ Ws,
                                          const _Float16* __restrict__ nextWs,
                                          const char* act, half8 (&w)[2][4],
                                          int wave, int lane, floatx4 (&acc)[4][8]){
  constexpr int FT  = N/64;                     // W frags per wave (disjoint feature rows)
  constexpr int NFT = (NEXTN>0)? NEXTN/64 : 0;
  const int kg = lane>>4, col = lane&15;
  const int j0  = wave*(N/4);
  const int j0n = wave*(NEXTN/4);
  #pragma unroll
  for (int kk=0; kk<8; ++kk){
    if (kk < 7){
      #pragma unroll
      for (int ft=0; ft<FT; ++ft)
        w[(kk+1)&1][ft] = *(const half8*)&Ws[(size_t)(((kk+1)*4+kg)*N + j0 + ft*16 + col)*8];
    } else if constexpr (NEXTN > 0){
      #pragma unroll
      for (int ft=0; ft<NFT; ++ft)
        w[0][ft] = *(const half8*)&nextWs[(size_t)(kg*NEXTN + j0n + ft*16 + col)*8];
    }
    half8 a[8];
    #pragma unroll
    for (int et=0; et<8; ++et)
      a[et] = *(const half8*)(act + (size_t)(kk*4+kg)*CHS + (et*16 + col)*16);
    __builtin_amdgcn_s_setprio(1);
    #pragma unroll
    for (int ft=0; ft<FT; ++ft)
      #pragma unroll
      for (int et=0; et<8; ++et)
        acc[ft][et] = MFMA16(w[kk&1][ft], a[et], acc[ft][et]);
    __builtin_amdgcn_s_setprio(0);
  }
}

// epilogue: lane (rg,col) holds features jb..jb+3 (jb = j0+ft*16+rg*4) of edge et*16+col
// -> one half4 (b64) LDS store per (ft,et); bias read as float4 from LDS.
template<int N>
__device__ __forceinline__ void epi_relu(floatx4 (&acc)[4][8], const float* __restrict__ biasf,
                                         int boff, char* act, int wave, int lane){
  constexpr int FT = N/64;
  const int rg = lane>>4, col = lane&15;
  #pragma unroll
  for (int ft=0; ft<FT; ++ft){
    const int jb = wave*(N/4) + ft*16 + rg*4;
    const floatx4 bv = *(const floatx4*)&biasf[boff + jb];
    char* dst = act + (size_t)(jb>>3)*CHS + (size_t)(jb&7)*2;
    #pragma unroll
    for (int et=0; et<8; ++et){
      int e = et*16 + col;
      half4 o;
      #pragma unroll
      for (int r=0; r<4; ++r){
        o[r] = (_Float16)fmaxf(acc[ft][et][r] + bv[r], 0.f);
        acc[ft][et][r] = 0.f;
      }
      *(half4*)(dst + (size_t)e*16) = o;
    }
  }
}

__global__ __launch_bounds__(256,2) void msg_kernel(
    const _Float16* __restrict__ h,
    const int* __restrict__ src_csr, const int* __restrict__ dst_csr,
    const _Float16* __restrict__ W1s, const _Float16* __restrict__ W2s,
    const _Float16* __restrict__ W3s, const _Float16* __restrict__ W4s,
    const float* __restrict__ msgbias,
    _Float16* __restrict__ messages){
  __shared__ __align__(16) char smem[32*CHS + 4096];   // 69.5KB -> 2 blocks/CU
  char* act = smem;
  const float* biasf = (const float*)(smem + 32*CHS);
  const int t = threadIdx.x, wave = t>>6, lane = t&63;
  const int kg = lane>>4, col = lane&15;
  const int e0 = blockIdx.x*128;
  // stage bias concat (1024 floats; wave w loads 1KB)
  load_lds16((const char*)msgbias + wave*1024 + lane*16, smem + 32*CHS + wave*1024);
  // gather msg_in = [h[src] | h[dst]] into act chunks (0..15 src, 16..31 dst)
  {
    const int* ids = (wave < 2) ? src_csr : dst_csr;
    const int row0 = ids[e0 + lane]      * NFEAT;
    const int row1 = ids[e0 + 64 + lane] * NFEAT;
    #pragma unroll
    for (int i=0;i<8;++i){
      int c = wave*8 + i;
      int f = (c&15)*8;
      load_lds16(h + row0 + f, act + (size_t)c*CHS);
      load_lds16(h + row1 + f, act + (size_t)c*CHS + 1024);
    }
  }
  // L1 K-step-0 W prefetch (global -> regs): wave owns feature rows wave*64..+63
  half8 w[2][4];
  #pragma unroll
  for (int ft=0; ft<4; ++ft)
    w[0][ft] = *(const half8*)&W1s[(size_t)(kg*256 + wave*64 + ft*16 + col)*8];

  floatx4 acc[4][8];
  const floatx4 fz = {0.f,0.f,0.f,0.f};
  #pragma unroll
  for (int i=0;i<4;++i)
    #pragma unroll
    for (int j=0;j<8;++j) acc[i][j] = fz;

  WAITV0(); SBAR();                    // act + bias staged everywhere

  run_layer<256,256>(W1s, W2s, act, w, wave, lane, acc);
  WAITLGKM(); SBAR();                  // all waves' act reads done
  epi_relu<256>(acc, biasf, 0, act, wave, lane);
  WAITLGKM(); SBAR();                  // epi writes visible
  run_layer<256,256>(W2s, W3s, act, w, wave, lane, acc);
  WAITLGKM(); SBAR();
  epi_relu<256>(acc, biasf, 256, act, wave, lane);
  WAITLGKM(); SBAR();
  run_layer<256,128>(W3s, W4s, act, w, wave, lane, acc);
  WAITLGKM(); SBAR();
  epi_relu<256>(acc, biasf, 512, act, wave, lane);
  WAITLGKM(); SBAR();
  run_layer<128,0>(W4s, nullptr, act, w, wave, lane, acc);
  // L4 epilogue -> messages in CSR-slot order, includes b4.
  // lane holds features jb..jb+3 (jb = wave*32+ft*16+rg*4) of edge et*16+col -> half4 store.
  {
    const int rg = lane>>4;
    #pragma unroll
    for (int ft=0; ft<2; ++ft){
      const int jb = wave*32 + ft*16 + rg*4;
      const floatx4 bv = *(const floatx4*)&biasf[768 + jb];
      #pragma unroll
      for (int et=0; et<8; ++et){
        int e = e0 + et*16 + col;
        half4 o;
        #pragma unroll
        for (int r=0; r<4; ++r) o[r] = (_Float16)(acc[ft][et][r] + bv[r]);
        *(half4*)&messages[(size_t)e*NEDGE + jb] = o;
      }
    }
  }
}

// ---------------- fused agg + GRU + output projection, 64 nodes, 8 waves ----------------
// agg: 32 slots x 16 lanes x half8 (256 B/row coalesced). Per node: fixed burst of 8
// clamped-index loads issued back-to-back (len<=8 covers ~97%; rare tail loops).
// If m0v != nullptr (iteration 0, h0==0): agg = deg(n)*m0, gh == 0, h_old == 0 --
// no h16 read/staging at all (h16 is write-only here, defined for iteration 1).
// h is pure-fp16 recurrent state; h_old from A2 LDS (read-before-write bijective).
__global__ __launch_bounds__(512,1) void gru_kernel(
    const _Float16* __restrict__ messages,
    const int* __restrict__ rowptr,
    const _Float16* __restrict__ nin16,
    _Float16* __restrict__ h16,
    const _Float16* __restrict__ Wihs, const _Float16* __restrict__ Whhs,
    const _Float16* __restrict__ Wfs,
    const float* __restrict__ b_ih, const float* __restrict__ b_hh,
    const float* __restrict__ b_f,
    float* __restrict__ out,
    const _Float16* __restrict__ m0v){
  __shared__ _Float16 A1[24*64*8];   // gru_in: chunks 0..15 agg, 16..23 node inputs
  __shared__ _Float16 A2[16*64*8];   // h rows (K=128); later reused for h_new
  const int t = threadIdx.x, wave = t>>6, lane = t&63;
  const int kg = lane>>4, col = lane&15;
  const int n0 = blockIdx.x*64;
  load_lds16(nin16 + (size_t)(n0+lane)*NIN + wave*8, (char*)A1 + (size_t)(16+wave)*1024);
  if (!m0v){
    #pragma unroll
    for (int ii=0; ii<2; ++ii){
      int c = wave*2 + ii;
      load_lds16(h16 + (size_t)(n0+lane)*NFEAT + c*8, (char*)A2 + (size_t)c*1024);
    }
  }
  // agg -> A1 chunks 0..15
  {
    const int slot = t>>4, chunk = t&15, l8 = (t&15)*8;  // 32 slots x 16 feat-lanes
    #pragma unroll
    for (int rr=0; rr<2; ++rr){
      const int nl = rr*32 + slot;
      const int beg = rowptr[n0 + nl], end = rowptr[n0 + nl + 1];
      float a[8] = {0.f,0.f,0.f,0.f,0.f,0.f,0.f,0.f};
      if (m0v){
        const float s = (float)(end - beg);
        #pragma unroll
        for (int q=0; q<8; ++q) a[q] = s * (float)m0v[l8+q];
      } else {
        const int len = end - beg;
        const int safe = (beg < N_EDGES) ? beg : (N_EDGES-1);
        half8 v[8];
        #pragma unroll
        for (int k=0; k<8; ++k){
          int idx = beg + k;
          idx = (idx < end) ? idx : safe;          // clamped: always a valid address
          v[k] = *(const half8*)(messages + (size_t)idx*NEDGE + l8);
        }
        #pragma unroll
        for (int k=0; k<8; ++k){
          if (k < len){
            #pragma unroll
            for (int q=0; q<8; ++q) a[q] += (float)v[k][q];
          }
        }
        for (int idx = beg+8; idx < end; ++idx){   // rare tail (len>8)
          half8 w = *(const half8*)(messages + (size_t)idx*NEDGE + l8);
          #pragma unroll
          for (int q=0; q<8; ++q) a[q] += (float)w[q];
        }
      }
      half8 o;
      #pragma unroll
      for (int q=0; q<8; ++q) o[q] = (_Float16)a[q];
      *(half8*)&A1[((size_t)chunk*64 + nl)*8] = o;
    }
  }
  floatx4 gi[3][4], gh[3][4];
  const floatx4 fz = {0.f,0.f,0.f,0.f};
  #pragma unroll
  for (int g=0; g<3; ++g)
    #pragma unroll
    for (int mt=0; mt<4; ++mt){ gi[g][mt]=fz; gh[g][mt]=fz; }

  __syncthreads();   // staging (vmcnt) + agg ds_writes (lgkm) all visible

  // wave w owns features w*16..w*16+15 (all 3 gates)
  #pragma unroll
  for (int kk=0; kk<6; ++kk){
    half8 a[4];
    #pragma unroll
    for (int mt=0;mt<4;++mt)
      a[mt] = *(const half8*)&A1[(((kk*4+kg)*64) + mt*16 + col)*8];
    #pragma unroll
    for (int g=0; g<3; ++g){
      int j = g*128 + wave*16 + col;
      half8 b = *(const half8*)&Wihs[(size_t)((kk*4+kg)*384 + j)*8];
      #pragma unroll
      for (int mt=0;mt<4;++mt)
        gi[g][mt] = MFMA16(a[mt], b, gi[g][mt]);
    }
  }
  if (!m0v){
    #pragma unroll
    for (int kk=0; kk<4; ++kk){
      half8 a[4];
      #pragma unroll
      for (int mt=0;mt<4;++mt)
        a[mt] = *(const half8*)&A2[(((kk*4+kg)*64) + mt*16 + col)*8];
      #pragma unroll
      for (int g=0; g<3; ++g){
        int j = g*128 + wave*16 + col;
        half8 b = *(const half8*)&Whhs[(size_t)((kk*4+kg)*384 + j)*8];
        #pragma unroll
        for (int mt=0;mt<4;++mt)
          gh[g][mt] = MFMA16(a[mt], b, gh[g][mt]);
      }
    }
  }
  __syncthreads();   // all A2 (h_old) MFMA reads done before overwrite

  // gates + h update; h_old from A2 LDS (read-before-write, unique slot per thread);
  // h_new -> global fp16 and back into A2 for the W_f GEMM
  {
    int jl = wave*16 + col;     // feature 0..127
    float bir=b_ih[jl], biz=b_ih[128+jl], bin_=b_ih[256+jl];
    float bhr=b_hh[jl], bhz=b_hh[128+jl], bhn=b_hh[256+jl];
    #pragma unroll
    for (int mt=0; mt<4; ++mt){
      #pragma unroll
      for (int r=0; r<4; ++r){
        int e = mt*16 + kg*4 + r;
        float ir = gi[0][mt][r] + bir;
        float iz = gi[1][mt][r] + biz;
        float inn= gi[2][mt][r] + bin_;
        float hr = gh[0][mt][r] + bhr;
        float hz = gh[1][mt][r] + bhz;
        float hn = gh[2][mt][r] + bhn;
        float rg2 = 1.f/(1.f+__expf(-(ir+hr)));
        float zg  = 1.f/(1.f+__expf(-(iz+hz)));
        float ng  = tanhf(inn + rg2*hn);
        size_t slot2 = (size_t)(((jl>>3)*64) + e)*8 + (jl&7);
        float hold = m0v ? 0.f : (float)A2[slot2];
        float hnew = (1.f-zg)*ng + zg*hold;
        h16[(size_t)(n0+e)*NFEAT + jl] = (_Float16)hnew;
        A2[slot2] = (_Float16)hnew;
      }
    }
  }
  __syncthreads();

  // out = h_new @ W_f^T + b_f  (K=128 -> 64 cols; waves 0..3 own 16 cols each)
  if (wave < 4){
    floatx4 facc[4];
    #pragma unroll
    for (int mt=0;mt<4;++mt) facc[mt]=fz;
    #pragma unroll
    for (int kk=0; kk<4; ++kk){
      half8 a[4];
      #pragma unroll
      for (int mt=0;mt<4;++mt)
        a[mt] = *(const half8*)&A2[(((kk*4+kg)*64) + mt*16 + col)*8];
      half8 b = *(const half8*)&Wfs[(size_t)((kk*4+kg)*64 + wave*16 + col)*8];
      #pragma unroll
      for (int mt=0;mt<4;++mt)
        facc[mt] = MFMA16(a[mt], b, facc[mt]);
    }
    float bf = b_f[wave*16+col];
    #pragma unroll
    for (int mt=0; mt<4; ++mt){
      #pragma unroll
      for (int r=0; r<4; ++r){
        int e = mt*16 + kg*4 + r;
        out[(size_t)(n0+e)*NOUTD + wave*16 + col] = facc[mt][r] + bf;
      }
    }
  }
}

// ---------------- launch ----------------
extern "C" void kernel_launch(void* const* d_in, const int* in_sizes, int n_in,
                              void* d_out, int out_size, void* d_ws, size_t ws_size,
                              hipStream_t stream){
  (void)in_sizes; (void)n_in; (void)out_size; (void)ws_size;
  const float* node_inputs = (const float*)d_in[0];
  const int*   src_ids = (const int*)d_in[1];
  const int*   dst_ids = (const int*)d_in[2];
  const float* W1 = (const float*)d_in[3];  const float* b1 = (const float*)d_in[4];
  const float* W2 = (const float*)d_in[5];  const float* b2 = (const float*)d_in[6];
  const float* W3 = (const float*)d_in[7];  const float* b3 = (const float*)d_in[8];
  const float* W4 = (const float*)d_in[9];  const float* b4 = (const float*)d_in[10];
  const float* W_ih = (const float*)d_in[11];
  const float* W_hh = (const float*)d_in[12];
  const float* b_ih = (const float*)d_in[13];
  const float* b_hh = (const float*)d_in[14];
  const float* W_f  = (const float*)d_in[15];
  const float* b_f  = (const float*)d_in[16];
  float* out = (float*)d_out;

  char* ws = (char*)d_ws;
  auto alloc = [&](size_t b){ char* p = ws; ws += (b + 255) & ~(size_t)255; return p; };
  _Float16* h16  = (_Float16*)alloc((size_t)N_NODES*NFEAT*2);
  _Float16* nin16= (_Float16*)alloc((size_t)N_NODES*NIN*2);
  _Float16* msgs = (_Float16*)alloc((size_t)N_EDGES*NEDGE*2);
  _Float16* W1s  = (_Float16*)alloc(256*256*2);
  _Float16* W2s  = (_Float16*)alloc(256*256*2);
  _Float16* W3s  = (_Float16*)alloc(256*256*2);
  _Float16* W4s  = (_Float16*)alloc(128*256*2);
  _Float16* Wihs = (_Float16*)alloc(384*192*2);
  _Float16* Whhs = (_Float16*)alloc(384*128*2);
  _Float16* Wfs  = (_Float16*)alloc(64*128*2);
  float* msgbias = (float*)alloc(1024*4);
  _Float16* m0   = (_Float16*)alloc(128*2);
  int* cnt     = (int*)alloc((size_t)N_NODES*4);
  int* rowptr  = (int*)alloc((size_t)(N_NODES+1)*4);
  int* offs    = (int*)alloc((size_t)N_NODES*4);
  int* src_csr = (int*)alloc((size_t)N_EDGES*4);
  int* dst_csr = (int*)alloc((size_t)N_EDGES*4);

  setup_kernel<<<4096+64+176+4,256,0,stream>>>(
      node_inputs, W1,W2,W3,W4, W_ih,W_hh,W_f, b1,b2,b3,b4,
      nin16, W1s,W2s,W3s,W4s, Wihs,Whhs,Wfs, msgbias, cnt);
  hist_kernel<<<N_EDGES/256,256,0,stream>>>(dst_ids, cnt);
  scan_kernel<<<2,1024,0,stream>>>(cnt, rowptr, offs, W2, W3, W4, b1, b2, b3, b4, m0);
  scatter_kernel<<<N_EDGES/256,256,0,stream>>>(src_ids, dst_ids, offs, src_csr, dst_csr);

  // iteration 0: h0==0 -> messages are all m0; skip msg_kernel, gh==0, no h16 read
  gru_kernel<<<N_NODES/64,512,0,stream>>>(msgs, rowptr, nin16, h16,
                                          Wihs, Whhs, Wfs, b_ih, b_hh, b_f,
                                          out, m0);
  for (int it=1; it<NITERS; ++it){
    msg_kernel<<<N_EDGES/128,256,0,stream>>>(h16, src_csr, dst_csr,
                                             W1s,W2s,W3s,W4s, msgbias, msgs);
    gru_kernel<<<N_NODES/64,512,0,stream>>>(msgs, rowptr, nin16, h16,
                                            Wihs, Whhs, Wfs, b_ih, b_hh, b_f,
                                            out + (size_t)it*N_NODES*NOUTD, nullptr);
  }
}